// Round 6
// baseline (313.670 us; speedup 1.0000x reference)
//
#include <hip/hip_runtime.h>
#include <hip/hip_bf16.h>
#include <math.h>

// MultiheadAttention: B=4,S=2048,E=1024,H=16,DK=64, fp32 in/out.
// All-fp16 MFMA; static-max softmax in exp2 domain.
// GEMMs v4 (R5, confirmed win): 128x128 tile, BK=64, granule XOR-swizzle,
// per-XCD 4m x 8n supertile walk (3MB concurrent working set < 4MB L2).
// attn v4: K/V staged via global_load_lds into LINEAR LDS with the
// GEMM-proven source-granule XOR swizzle (0-conflict fragment reads);
// register staging (kr/vr, 32 VGPRs) deleted -> fits launch_bounds(256,4)
// (unified 128-reg cap splits ~64 arch + 64 acc; R1 spilled because
// reg-staging needed ~96 arch). Grid 1024 = exactly 4 blocks/CU, no tail.
// P stays in registers via permlane32/16_swap.

typedef _Float16 f16x8 __attribute__((ext_vector_type(8)));
typedef _Float16 f16x4 __attribute__((ext_vector_type(4)));
typedef _Float16 f16x2 __attribute__((ext_vector_type(2)));
typedef float    f32x4 __attribute__((ext_vector_type(4)));
typedef unsigned int u32x2 __attribute__((ext_vector_type(2)));
typedef unsigned int u32x4 __attribute__((ext_vector_type(4)));

#define MFMA16(a,b,c) __builtin_amdgcn_mfma_f32_16x16x32_f16(a,b,c,0,0,0)

__device__ __forceinline__ void async_cp16(const _Float16* g, _Float16* l) {
    __builtin_amdgcn_global_load_lds(
        (const __attribute__((address_space(1))) unsigned int*)g,
        (__attribute__((address_space(3))) unsigned int*)l,
        16, 0, 0);
}

__device__ __forceinline__ f16x2 pk(float a, float b) {
    return __builtin_bit_cast(f16x2, __builtin_amdgcn_cvt_pkrtz(a, b));
}

// ---- weight transpose (coalesced, via LDS) + cvt: W (K x N) -> WT fp16 (N x K) ----
__global__ void __launch_bounds__(256) prep_weights(
    const float* __restrict__ Wq, const float* __restrict__ Wk,
    const float* __restrict__ Wv, const float* __restrict__ Wo,
    _Float16* __restrict__ wt)
{
    __shared__ float tile[32][33];
    int mat = blockIdx.y;
    const float* W = (mat==0)?Wq:(mat==1)?Wk:(mat==2)?Wv:Wo;
    _Float16* WT = wt + (size_t)mat*1048576;
    int t = blockIdx.x;              // 0..1023
    int kb = (t & 31) * 32;
    int nb = (t >> 5) * 32;
    int tx = threadIdx.x & 31, ty = threadIdx.x >> 5;   // ty 0..7
    #pragma unroll
    for (int r = 0; r < 4; ++r) {
        int row = ty + r*8;
        tile[row][tx] = W[(size_t)(kb+row)*1024 + nb + tx];
    }
    __syncthreads();
    #pragma unroll
    for (int r = 0; r < 4; ++r) {
        int row = ty + r*8;
        WT[(size_t)(nb+row)*1024 + kb + tx] = (_Float16)tile[tx][row];
    }
}

// ---- X (8192x1024 fp32) -> fp16 ----
__global__ void __launch_bounds__(256) cvt_x(
    const float* __restrict__ X, _Float16* __restrict__ Xh)
{
    int i = (blockIdx.x*256 + threadIdx.x)*4;
    f32x4 x = *(const f32x4*)&X[i];
    f16x4 h;
    #pragma unroll
    for (int k=0;k<4;k++) h[k] = (_Float16)x[k];
    *(f16x4*)&Xh[i] = h;
}

// ---- fused QKV projection GEMM: C = X * W^T + b, 128x128 tile, BK=64 ----
// grid 1536: xcd = id&7; per-XCD lid walks a 4m x 8n supertile:
//   lid = (ng:3)(mq:2)(m_lo:4)(nb:8)  ->  32-block windows share
//   4 A-panels + 8 B-panels = 3MB (fits 4MB L2).
__global__ void __launch_bounds__(256) gemm_qkv(
    const _Float16* __restrict__ Xh, const _Float16* __restrict__ wt,
    const float* __restrict__ bq, const float* __restrict__ bk, const float* __restrict__ bv,
    _Float16* __restrict__ Q, _Float16* __restrict__ K, _Float16* __restrict__ Vt)
{
    __shared__ __align__(16) _Float16 sA[8192];   // 128 x 64, xor-swizzled granules
    __shared__ __align__(16) _Float16 sB[8192];

    const int id = blockIdx.x;
    const int xcd = id & 7;
    const int lid = id >> 3;          // 0..191 per XCD
    const int ng  = lid / 64;         // 0..2  (nblk group of 8)
    const int rem = lid % 64;
    const int mq  = rem >> 5;         // 0..1  (4-mblk quarter)
    const int r2  = rem & 31;
    const int m_lo = r2 >> 3;         // 0..3
    const int nb   = r2 & 7;          // 0..7
    const int mblk = (mq*4 + m_lo)*8 + xcd;   // 0..63
    const int nblk = ng*8 + nb;               // 0..23

    const int tid = threadIdx.x;
    const int wave = tid >> 6, lane = tid & 63;
    const int wr = wave >> 1, wc = wave & 1;
    const int q4 = lane >> 4, cc = lane & 15;

    const int mat = nblk >> 3;               // 0=q 1=k 2=v
    const int colbase = (nblk & 7) * 128;
    const _Float16* Bg = wt + (size_t)mat*1048576 + (size_t)colbase*1024;
    const _Float16* Ag = Xh + (size_t)mblk*131072;

    f32x4 acc[4][4] = {};

    const int srow = tid >> 3;                              // 0..31
    const int scg  = ((tid & 7) ^ ((tid >> 3) & 7)) * 8;    // swizzled source granule

    for (int kb = 0; kb < 1024; kb += 64) {
        __syncthreads();
        #pragma unroll
        for (int rr = 0; rr < 4; ++rr) {
            async_cp16(&Ag[(size_t)(rr*32 + srow)*1024 + kb + scg], sA + rr*2048 + wave*512);
            async_cp16(&Bg[(size_t)(rr*32 + srow)*1024 + kb + scg], sB + rr*2048 + wave*512);
        }
        __syncthreads();
        #pragma unroll
        for (int ks = 0; ks < 2; ++ks) {
            f16x8 af[4], bf[4];
            #pragma unroll
            for (int i=0;i<4;i++){
                af[i] = *(const f16x8*)&sA[(wr*64+i*16+cc)*64 + ((ks*4+q4)^(cc&7))*8];
                bf[i] = *(const f16x8*)&sB[(wc*64+i*16+cc)*64 + ((ks*4+q4)^(cc&7))*8];
            }
            #pragma unroll
            for (int i=0;i<4;i++)
                #pragma unroll
                for (int j=0;j<4;j++)
                    acc[i][j] = MFMA16(af[i], bf[j], acc[i][j]);
        }
    }

    const float* bias = (mat==0)?bq:(mat==1)?bk:bv;
    const float QSCALE = 0.125f * 1.44269504f;
    #pragma unroll
    for (int i=0;i<4;i++)
      #pragma unroll
      for (int j=0;j<4;j++)
        #pragma unroll
        for (int r=0;r<4;r++){
            int m = mblk*128 + wr*64 + i*16 + q4*4 + r;
            int ncol = colbase + wc*64 + j*16 + cc;     // 0..1023 in matrix
            float val = acc[i][j][r] + bias[ncol];
            int b = m >> 11, s = m & 2047;
            int h = ncol >> 6, dk = ncol & 63;
            if (mat == 2) {
                Vt[((size_t)(b*16+h)*64 + dk)*2048 + s] = (_Float16)val;  // V^T: (B,H,DK,S)
            } else {
                size_t qi = ((size_t)(b*16+h)*2048 + s)*64 + dk;          // (B,H,S,DK)
                if (mat == 0) Q[qi] = (_Float16)(val * QSCALE);
                else          K[qi] = (_Float16)val;
            }
        }
}

// ---- output projection: out = ctx * Wo^T + bo, BK=64, swizzled LDS ----
// grid 512: xcd = id&7; per-XCD 64 blocks walk a 4m x 8n supertile.
__global__ void __launch_bounds__(256) gemm_out(
    const _Float16* __restrict__ Ctx, const _Float16* __restrict__ wt,
    const float* __restrict__ bo,
    float* __restrict__ out)
{
    __shared__ __align__(16) _Float16 sA[8192];
    __shared__ __align__(16) _Float16 sB[8192];

    const int id = blockIdx.x;        // 0..511
    const int xcd = id & 7;
    const int lid = id >> 3;          // 0..63 per XCD
    const int mq  = lid >> 5;         // 0..1
    const int r2  = lid & 31;
    const int m_lo = r2 >> 3;         // 0..3
    const int nblk = r2 & 7;          // 0..7
    const int mblk = (mq*4 + m_lo)*8 + xcd;   // 0..63

    const int tid = threadIdx.x;
    const int wave = tid >> 6, lane = tid & 63;
    const int wr = wave >> 1, wc = wave & 1;
    const int q4 = lane >> 4, cc = lane & 15;

    const _Float16* Bg = wt + (size_t)3*1048576 + (size_t)nblk*128*1024;
    const _Float16* Ag = Ctx + (size_t)mblk*131072;

    f32x4 acc[4][4] = {};
    const int srow = tid >> 3;
    const int scg  = ((tid & 7) ^ ((tid >> 3) & 7)) * 8;

    for (int kb = 0; kb < 1024; kb += 64) {
        __syncthreads();
        #pragma unroll
        for (int rr = 0; rr < 4; ++rr) {
            async_cp16(&Ag[(size_t)(rr*32 + srow)*1024 + kb + scg], sA + rr*2048 + wave*512);
            async_cp16(&Bg[(size_t)(rr*32 + srow)*1024 + kb + scg], sB + rr*2048 + wave*512);
        }
        __syncthreads();
        #pragma unroll
        for (int ks = 0; ks < 2; ++ks) {
            f16x8 af[4], bf[4];
            #pragma unroll
            for (int i=0;i<4;i++){
                af[i] = *(const f16x8*)&sA[(wr*64+i*16+cc)*64 + ((ks*4+q4)^(cc&7))*8];
                bf[i] = *(const f16x8*)&sB[(wc*64+i*16+cc)*64 + ((ks*4+q4)^(cc&7))*8];
            }
            #pragma unroll
            for (int i=0;i<4;i++)
                #pragma unroll
                for (int j=0;j<4;j++)
                    acc[i][j] = MFMA16(af[i], bf[j], acc[i][j]);
        }
    }

    #pragma unroll
    for (int i=0;i<4;i++)
      #pragma unroll
      for (int j=0;j<4;j++)
        #pragma unroll
        for (int r=0;r<4;r++){
            int m = mblk*128 + wr*64 + i*16 + q4*4 + r;
            int n = nblk*128 + wc*64 + j*16 + cc;
            out[(size_t)m*1024 + n] = acc[i][j][r] + bo[n];
        }
}

// ---- flash attention, static-max softmax: 128 q-rows/block, 128-key tiles ----
// 1-D grid 1024: XCD = id%8; each XCD runs one head's 16 q-chunks before the
// next head (512 KB K/V live per XCD L2, fetched once).
// K/V staged direct-to-LDS (global_load_lds) into linear sK[128x64] /
// sV[64x128] with source-granule XOR swizzle; fragment reads use the same
// XOR -> conflict-free (GEMM-proven). P never touches LDS: after swapped
// QK^T (lane holds keys kj*16+q4*4+r of q-row cc), the PV A-fragment
// (keys 32ks+8q4+j) is built with permlane32_swap -> permlane16_swap.
__global__ void __launch_bounds__(256,4) attn(
    const _Float16* __restrict__ Qg, const _Float16* __restrict__ Kg,
    const _Float16* __restrict__ Vg,
    _Float16* __restrict__ Ctx)
{
    __shared__ __align__(16) _Float16 sK[8192];   // 128 x 64, swizzled granules
    __shared__ __align__(16) _Float16 sV[8192];   // 64 x 128, swizzled granules
    __shared__ float sL[128];

    const int id = blockIdx.x;
    const int xcd = id & 7;
    const int t2 = id >> 3;           // 0..127
    const int qc = t2 & 15;
    const int bh = (t2 >> 4) * 8 + xcd;

    const int tid = threadIdx.x;
    const int wave = tid >> 6, lane = tid & 63;
    const int q4 = lane >> 4, cc = lane & 15;

    const size_t hoff = (size_t)bh * 131072;   // 2048*64
    const _Float16* Qp = Qg + hoff;
    const _Float16* Kp = Kg + hoff;
    const _Float16* Vp = Vg + hoff;

    const int qbase = qc*128 + wave*32;

    f16x8 qf[2][2];
    #pragma unroll
    for (int m=0;m<2;m++)
      #pragma unroll
      for (int ks=0;ks<2;ks++)
        qf[m][ks] = *(const f16x8*)&Qp[(qbase+m*16+cc)*64 + ks*32 + q4*8];

    f32x4 o[2][4] = {};
    float lsum[2] = {0.f, 0.f};

    // staging indices (same derivation as the GEMMs):
    // K: 4 rounds x 32 rows; dest granule = rr*256+tid; row=rr*32+(tid>>3),
    //    stored pos p=tid&7 holds true granule p^(row&7).
    const int srow = tid >> 3;                             // 0..31
    const int scg  = ((tid & 7) ^ ((tid >> 3) & 7)) * 8;   // K source granule
    // V: 4 rounds x 16 rows; dest granule = rr*256+tid; row=rr*16+(tid>>4),
    //    stored pos p=tid&15 holds true granule p^(row&7).
    const int vrow = tid >> 4;                             // 0..15
    const int vsg  = ((tid & 15) ^ ((tid >> 4) & 7)) * 8;  // V source granule

    for (int kt = 0; kt < 16; ++kt) {
        __syncthreads();   // prev QK/PV reads of sK/sV done
        const _Float16* Kb = Kp + kt*8192;
        const _Float16* Vb = Vp + (size_t)kt*128;
        #pragma unroll
        for (int rr = 0; rr < 4; ++rr) {
            async_cp16(&Kb[(rr*32 + srow)*64 + scg],          sK + rr*2048 + wave*512);
            async_cp16(&Vb[(size_t)(rr*16 + vrow)*2048 + vsg], sV + rr*2048 + wave*512);
        }
        asm volatile("s_waitcnt vmcnt(0)" ::: "memory");
        __syncthreads();   // tiles staged

        // k-slice major: QK^T for kj=2ks,2ks+1 -> exp2 -> pack -> permlane
        // exchange -> PV for slice ks. P registers are transient per slice.
        #pragma unroll
        for (int ks=0;ks<4;ks++){
            unsigned Ud[2][2], Wd[2][2];   // [m][dword]; U: kj=2ks, W: kj=2ks+1
            #pragma unroll
            for (int aa=0;aa<2;aa++){
                int kj = ks*2 + aa;
                // row = kj*16+cc (row&7 == cc&7); true granule g read at pos g^(cc&7)
                f16x8 k0 = *(const f16x8*)&sK[(kj*16+cc)*64 + ((q4    ^(cc&7))*8)];
                f16x8 k1 = *(const f16x8*)&sK[(kj*16+cc)*64 + (((4+q4)^(cc&7))*8)];
                #pragma unroll
                for (int m=0;m<2;m++){
                    f32x4 z = {};
                    f32x4 s = MFMA16(k0, qf[m][0], z);
                    s = MFMA16(k1, qf[m][1], s);
                    float p0 = __builtin_amdgcn_exp2f(s[0]);
                    float p1 = __builtin_amdgcn_exp2f(s[1]);
                    float p2 = __builtin_amdgcn_exp2f(s[2]);
                    float p3 = __builtin_amdgcn_exp2f(s[3]);
                    lsum[m] += (p0 + p1) + (p2 + p3);
                    unsigned d0 = __builtin_bit_cast(unsigned, pk(p0, p1));
                    unsigned d1 = __builtin_bit_cast(unsigned, pk(p2, p3));
                    if (aa == 0) { Ud[m][0] = d0; Ud[m][1] = d1; }
                    else         { Wd[m][0] = d0; Wd[m][1] = d1; }
                }
            }
            // A-frag: lane (cc,q4) needs keys 32ks+8q4+{0..7} of q-row cc.
            f16x8 pa[2];
            #pragma unroll
            for (int m=0;m<2;m++){
                u32x2 x0 = __builtin_amdgcn_permlane32_swap(Ud[m][0], Wd[m][0], false, false);
                u32x2 r02 = __builtin_amdgcn_permlane16_swap(x0[0], x0[1], false, false);
                u32x2 x1 = __builtin_amdgcn_permlane32_swap(Ud[m][1], Wd[m][1], false, false);
                u32x2 r13 = __builtin_amdgcn_permlane16_swap(x1[0], x1[1], false, false);
                u32x4 pw;
                pw[0] = r02[0]; pw[1] = r13[0]; pw[2] = r02[1]; pw[3] = r13[1];
                pa[m] = __builtin_bit_cast(f16x8, pw);
            }
            #pragma unroll
            for (int v=0;v<4;v++){
                // row = v*16+cc (row&7 == cc&7); true granule ks*4+q4
                f16x8 vf = *(const f16x8*)&sV[(v*16+cc)*128 + (((ks*4+q4)^(cc&7))*8)];
                o[0][v] = MFMA16(pa[0], vf, o[0][v]);
                o[1][v] = MFMA16(pa[1], vf, o[1][v]);
            }
        }
    }

    // row sums: lane holds partial for q-row cc; reduce over the 4 q4-lanes,
    // then transpose cc -> (q4*4+r) through a tiny LDS buffer (per-wave region).
    #pragma unroll
    for (int m=0;m<2;m++){
        lsum[m] += __shfl_xor(lsum[m], 16, 64);
        lsum[m] += __shfl_xor(lsum[m], 32, 64);
    }
    if (q4 == 0) {
        sL[wave*32 + cc]      = lsum[0];
        sL[wave*32 + 16 + cc] = lsum[1];
    }
    __syncthreads();

    int b = bh >> 4, h = bh & 15;
    #pragma unroll
    for (int m=0;m<2;m++)
      #pragma unroll
      for (int r=0;r<4;r++){
        float inv = 1.f / sL[wave*32 + m*16 + q4*4 + r];
        int s = qbase + m*16 + q4*4 + r;
        #pragma unroll
        for (int v=0;v<4;v++){
            float val = o[m][v][r]*inv;
            int dk = v*16 + cc;
            Ctx[((size_t)(b*2048+s)*16 + h)*64 + dk] = (_Float16)val;  // (B,S,H,DK)
        }
      }
}

extern "C" void kernel_launch(void* const* d_in, const int* in_sizes, int n_in,
                              void* d_out, int out_size, void* d_ws, size_t ws_size,
                              hipStream_t stream)
{
    const float* q  = (const float*)d_in[0];
    const float* Wq = (const float*)d_in[1];
    const float* bq = (const float*)d_in[2];
    const float* Wk = (const float*)d_in[3];
    const float* bk = (const float*)d_in[4];
    const float* Wv = (const float*)d_in[5];
    const float* bv = (const float*)d_in[6];
    const float* Wo = (const float*)d_in[7];
    const float* bo = (const float*)d_in[8];
    float* out = (float*)d_out;

    _Float16* ws  = (_Float16*)d_ws;
    _Float16* wt  = ws;                   // 4 x 1M fp16 = 8MB
    _Float16* Xh  = ws + 4194304;         // 16MB
    _Float16* Q   = ws + 12582912;
    _Float16* K   = ws + 20971520;
    _Float16* Vt  = ws + 29360128;        // end 37748736 el = 75.5MB
    _Float16* Ctx = Xh;                   // X dead after gemm_qkv

    prep_weights<<<dim3(1024,4), 256, 0, stream>>>(Wq, Wk, Wv, Wo, wt);
    cvt_x<<<dim3(8192), 256, 0, stream>>>(q, Xh);
    gemm_qkv<<<dim3(1536), 256, 0, stream>>>(Xh, wt, bq, bk, bv, Q, K, Vt);
    attn<<<dim3(1024), 256, 0, stream>>>(Q, K, Vt, Ctx);
    gemm_out<<<dim3(512), 256, 0, stream>>>(Ctx, wt, bo, out);
}

// Round 8
// 295.514 us; speedup vs baseline: 1.0614x; 1.0614x over previous
//
#include <hip/hip_runtime.h>
#include <hip/hip_bf16.h>
#include <math.h>

// MultiheadAttention: B=4,S=2048,E=1024,H=16,DK=64, fp32 in/out.
// All-fp16 MFMA; static-max softmax in exp2 domain.
// GEMMs v4 (R5, confirmed win): 128x128 tile, BK=64, granule XOR-swizzle,
// per-XCD 4m x 8n supertile walk (3MB concurrent working set < 4MB L2).
// attn v6: K/V staged direct-to-LDS (global_load_lds) into DOUBLE-BUFFERED
// 64-key tiles (sK[2][64x64], sV[2][64x64], 33KB). R7 failed post-timing
// with the single-buffered variant (race: staging of tile t+1 vs reads of
// tile t separated only by a barrier the scheduler can leak across);
// double-buffering makes overwrite-before-read structurally impossible.
// Staging issued BEFORE compute -> L2 latency hidden under MFMA (T14).
// P stays in registers via permlane32/16_swap. launch_bounds(256,3):
// NEVER cap this body at 128 (R1/R6: ~100+ live regs -> 150-230MB spill).

typedef _Float16 f16x8 __attribute__((ext_vector_type(8)));
typedef _Float16 f16x4 __attribute__((ext_vector_type(4)));
typedef _Float16 f16x2 __attribute__((ext_vector_type(2)));
typedef float    f32x4 __attribute__((ext_vector_type(4)));
typedef unsigned int u32x2 __attribute__((ext_vector_type(2)));
typedef unsigned int u32x4 __attribute__((ext_vector_type(4)));

#define MFMA16(a,b,c) __builtin_amdgcn_mfma_f32_16x16x32_f16(a,b,c,0,0,0)

__device__ __forceinline__ void async_cp16(const _Float16* g, _Float16* l) {
    __builtin_amdgcn_global_load_lds(
        (const __attribute__((address_space(1))) unsigned int*)g,
        (__attribute__((address_space(3))) unsigned int*)l,
        16, 0, 0);
}

__device__ __forceinline__ f16x2 pk(float a, float b) {
    return __builtin_bit_cast(f16x2, __builtin_amdgcn_cvt_pkrtz(a, b));
}

// ---- weight transpose (coalesced, via LDS) + cvt: W (K x N) -> WT fp16 (N x K) ----
__global__ void __launch_bounds__(256) prep_weights(
    const float* __restrict__ Wq, const float* __restrict__ Wk,
    const float* __restrict__ Wv, const float* __restrict__ Wo,
    _Float16* __restrict__ wt)
{
    __shared__ float tile[32][33];
    int mat = blockIdx.y;
    const float* W = (mat==0)?Wq:(mat==1)?Wk:(mat==2)?Wv:Wo;
    _Float16* WT = wt + (size_t)mat*1048576;
    int t = blockIdx.x;              // 0..1023
    int kb = (t & 31) * 32;
    int nb = (t >> 5) * 32;
    int tx = threadIdx.x & 31, ty = threadIdx.x >> 5;   // ty 0..7
    #pragma unroll
    for (int r = 0; r < 4; ++r) {
        int row = ty + r*8;
        tile[row][tx] = W[(size_t)(kb+row)*1024 + nb + tx];
    }
    __syncthreads();
    #pragma unroll
    for (int r = 0; r < 4; ++r) {
        int row = ty + r*8;
        WT[(size_t)(nb+row)*1024 + kb + tx] = (_Float16)tile[tx][row];
    }
}

// ---- X (8192x1024 fp32) -> fp16 ----
__global__ void __launch_bounds__(256) cvt_x(
    const float* __restrict__ X, _Float16* __restrict__ Xh)
{
    int i = (blockIdx.x*256 + threadIdx.x)*4;
    f32x4 x = *(const f32x4*)&X[i];
    f16x4 h;
    #pragma unroll
    for (int k=0;k<4;k++) h[k] = (_Float16)x[k];
    *(f16x4*)&Xh[i] = h;
}

// ---- fused QKV projection GEMM: C = X * W^T + b, 128x128 tile, BK=64 ----
// grid 1536: xcd = id&7; per-XCD lid walks a 4m x 8n supertile:
//   lid = (ng:3)(mq:2)(m_lo:4)(nb:8)  ->  32-block windows share
//   4 A-panels + 8 B-panels = 3MB (fits 4MB L2).
__global__ void __launch_bounds__(256) gemm_qkv(
    const _Float16* __restrict__ Xh, const _Float16* __restrict__ wt,
    const float* __restrict__ bq, const float* __restrict__ bk, const float* __restrict__ bv,
    _Float16* __restrict__ Q, _Float16* __restrict__ K, _Float16* __restrict__ Vt)
{
    __shared__ __align__(16) _Float16 sA[8192];   // 128 x 64, xor-swizzled granules
    __shared__ __align__(16) _Float16 sB[8192];

    const int id = blockIdx.x;
    const int xcd = id & 7;
    const int lid = id >> 3;          // 0..191 per XCD
    const int ng  = lid / 64;         // 0..2  (nblk group of 8)
    const int rem = lid % 64;
    const int mq  = rem >> 5;         // 0..1  (4-mblk quarter)
    const int r2  = rem & 31;
    const int m_lo = r2 >> 3;         // 0..3
    const int nb   = r2 & 7;          // 0..7
    const int mblk = (mq*4 + m_lo)*8 + xcd;   // 0..63
    const int nblk = ng*8 + nb;               // 0..23

    const int tid = threadIdx.x;
    const int wave = tid >> 6, lane = tid & 63;
    const int wr = wave >> 1, wc = wave & 1;
    const int q4 = lane >> 4, cc = lane & 15;

    const int mat = nblk >> 3;               // 0=q 1=k 2=v
    const int colbase = (nblk & 7) * 128;
    const _Float16* Bg = wt + (size_t)mat*1048576 + (size_t)colbase*1024;
    const _Float16* Ag = Xh + (size_t)mblk*131072;

    f32x4 acc[4][4] = {};

    const int srow = tid >> 3;                              // 0..31
    const int scg  = ((tid & 7) ^ ((tid >> 3) & 7)) * 8;    // swizzled source granule

    for (int kb = 0; kb < 1024; kb += 64) {
        __syncthreads();
        #pragma unroll
        for (int rr = 0; rr < 4; ++rr) {
            async_cp16(&Ag[(size_t)(rr*32 + srow)*1024 + kb + scg], sA + rr*2048 + wave*512);
            async_cp16(&Bg[(size_t)(rr*32 + srow)*1024 + kb + scg], sB + rr*2048 + wave*512);
        }
        __syncthreads();
        #pragma unroll
        for (int ks = 0; ks < 2; ++ks) {
            f16x8 af[4], bf[4];
            #pragma unroll
            for (int i=0;i<4;i++){
                af[i] = *(const f16x8*)&sA[(wr*64+i*16+cc)*64 + ((ks*4+q4)^(cc&7))*8];
                bf[i] = *(const f16x8*)&sB[(wc*64+i*16+cc)*64 + ((ks*4+q4)^(cc&7))*8];
            }
            #pragma unroll
            for (int i=0;i<4;i++)
                #pragma unroll
                for (int j=0;j<4;j++)
                    acc[i][j] = MFMA16(af[i], bf[j], acc[i][j]);
        }
    }

    const float* bias = (mat==0)?bq:(mat==1)?bk:bv;
    const float QSCALE = 0.125f * 1.44269504f;
    #pragma unroll
    for (int i=0;i<4;i++)
      #pragma unroll
      for (int j=0;j<4;j++)
        #pragma unroll
        for (int r=0;r<4;r++){
            int m = mblk*128 + wr*64 + i*16 + q4*4 + r;
            int ncol = colbase + wc*64 + j*16 + cc;     // 0..1023 in matrix
            float val = acc[i][j][r] + bias[ncol];
            int b = m >> 11, s = m & 2047;
            int h = ncol >> 6, dk = ncol & 63;
            if (mat == 2) {
                Vt[((size_t)(b*16+h)*64 + dk)*2048 + s] = (_Float16)val;  // V^T: (B,H,DK,S)
            } else {
                size_t qi = ((size_t)(b*16+h)*2048 + s)*64 + dk;          // (B,H,S,DK)
                if (mat == 0) Q[qi] = (_Float16)(val * QSCALE);
                else          K[qi] = (_Float16)val;
            }
        }
}

// ---- output projection: out = ctx * Wo^T + bo, BK=64, swizzled LDS ----
// grid 512: xcd = id&7; per-XCD 64 blocks walk a 4m x 8n supertile.
__global__ void __launch_bounds__(256) gemm_out(
    const _Float16* __restrict__ Ctx, const _Float16* __restrict__ wt,
    const float* __restrict__ bo,
    float* __restrict__ out)
{
    __shared__ __align__(16) _Float16 sA[8192];
    __shared__ __align__(16) _Float16 sB[8192];

    const int id = blockIdx.x;        // 0..511
    const int xcd = id & 7;
    const int lid = id >> 3;          // 0..63 per XCD
    const int mq  = lid >> 5;         // 0..1
    const int r2  = lid & 31;
    const int m_lo = r2 >> 3;         // 0..3
    const int nblk = r2 & 7;          // 0..7
    const int mblk = (mq*4 + m_lo)*8 + xcd;   // 0..63

    const int tid = threadIdx.x;
    const int wave = tid >> 6, lane = tid & 63;
    const int wr = wave >> 1, wc = wave & 1;
    const int q4 = lane >> 4, cc = lane & 15;

    const _Float16* Bg = wt + (size_t)3*1048576 + (size_t)nblk*128*1024;
    const _Float16* Ag = Ctx + (size_t)mblk*131072;

    f32x4 acc[4][4] = {};
    const int srow = tid >> 3;
    const int scg  = ((tid & 7) ^ ((tid >> 3) & 7)) * 8;

    for (int kb = 0; kb < 1024; kb += 64) {
        __syncthreads();
        #pragma unroll
        for (int rr = 0; rr < 4; ++rr) {
            async_cp16(&Ag[(size_t)(rr*32 + srow)*1024 + kb + scg], sA + rr*2048 + wave*512);
            async_cp16(&Bg[(size_t)(rr*32 + srow)*1024 + kb + scg], sB + rr*2048 + wave*512);
        }
        __syncthreads();
        #pragma unroll
        for (int ks = 0; ks < 2; ++ks) {
            f16x8 af[4], bf[4];
            #pragma unroll
            for (int i=0;i<4;i++){
                af[i] = *(const f16x8*)&sA[(wr*64+i*16+cc)*64 + ((ks*4+q4)^(cc&7))*8];
                bf[i] = *(const f16x8*)&sB[(wc*64+i*16+cc)*64 + ((ks*4+q4)^(cc&7))*8];
            }
            #pragma unroll
            for (int i=0;i<4;i++)
                #pragma unroll
                for (int j=0;j<4;j++)
                    acc[i][j] = MFMA16(af[i], bf[j], acc[i][j]);
        }
    }

    #pragma unroll
    for (int i=0;i<4;i++)
      #pragma unroll
      for (int j=0;j<4;j++)
        #pragma unroll
        for (int r=0;r<4;r++){
            int m = mblk*128 + wr*64 + i*16 + q4*4 + r;
            int n = nblk*128 + wc*64 + j*16 + cc;
            out[(size_t)m*1024 + n] = acc[i][j][r] + bo[n];
        }
}

// ---- flash attention, static-max softmax: 128 q-rows/block, 64-key tiles ----
// 1-D grid 1024: XCD = id%8; each XCD runs one head's 16 q-chunks before the
// next head (512 KB K/V live per XCD L2, fetched once).
// Double-buffered K/V tiles via global_load_lds with source-granule XOR
// swizzle (linear dest; granule g of row r stored at position g^(r&7)).
// Per tile: issue next-tile DMA -> compute (QK^T, exp2 softmax, permlane P
// exchange, PV) -> vmcnt(0) -> barrier. One barrier per tile; overwrite of
// a buffer is >= one barrier after its last reader in EVERY wave's program
// order -> race-free regardless of scheduler hoisting.
__global__ void __launch_bounds__(256,3) attn(
    const _Float16* __restrict__ Qg, const _Float16* __restrict__ Kg,
    const _Float16* __restrict__ Vg,
    _Float16* __restrict__ Ctx)
{
    __shared__ __align__(16) _Float16 sK[2][4096];   // 64 keys x 64 dims
    __shared__ __align__(16) _Float16 sV[2][4096];   // 64 dims x 64 keys
    __shared__ float sL[128];

    const int id = blockIdx.x;
    const int xcd = id & 7;
    const int t2 = id >> 3;           // 0..127
    const int qc = t2 & 15;
    const int bh = (t2 >> 4) * 8 + xcd;

    const int tid = threadIdx.x;
    const int wave = tid >> 6, lane = tid & 63;
    const int q4 = lane >> 4, cc = lane & 15;

    const size_t hoff = (size_t)bh * 131072;   // 2048*64
    const _Float16* Qp = Qg + hoff;
    const _Float16* Kp = Kg + hoff;
    const _Float16* Vp = Vg + hoff;

    const int qbase = qc*128 + wave*32;

    f16x8 qf[2][2];
    #pragma unroll
    for (int m=0;m<2;m++)
      #pragma unroll
      for (int ks=0;ks<2;ks++)
        qf[m][ks] = *(const f16x8*)&Qp[(qbase+m*16+cc)*64 + ks*32 + q4*8];

    f32x4 o[2][4] = {};
    float lsum[2] = {0.f, 0.f};

    // staging: both K and V tiles are 64 rows x 64 f16, 2 rounds of
    // 256 lanes x 16B. row = rr*32 + (tid>>3); source granule (tid&7)^(row&7)
    // lands at dest position tid&7 (linear dest = base + lane*16B).
    const int srow = tid >> 3;                             // 0..31
    const int scg  = ((tid & 7) ^ ((tid >> 3) & 7)) * 8;   // source granule offset

    // prologue: stage tile 0 into buffer 0
    #pragma unroll
    for (int rr = 0; rr < 2; ++rr) {
        async_cp16(&Kp[(rr*32 + srow)*64 + scg],           &sK[0][rr*2048 + wave*512]);
        async_cp16(&Vp[(size_t)(rr*32 + srow)*2048 + scg], &sV[0][rr*2048 + wave*512]);
    }
    asm volatile("s_waitcnt vmcnt(0)" ::: "memory");
    __syncthreads();
    __builtin_amdgcn_sched_barrier(0);

    for (int kt = 0; kt < 32; ++kt) {
        const int cur = kt & 1;
        const _Float16* kc = &sK[cur][0];
        const _Float16* vc = &sV[cur][0];

        // issue next tile's DMA into the OTHER buffer (hidden under compute)
        if (kt < 31) {
            _Float16* kn = &sK[cur ^ 1][0];
            _Float16* vn = &sV[cur ^ 1][0];
            const _Float16* Kb = Kp + (size_t)(kt+1)*4096;
            const _Float16* Vb = Vp + (size_t)(kt+1)*64;
            #pragma unroll
            for (int rr = 0; rr < 2; ++rr) {
                async_cp16(&Kb[(rr*32 + srow)*64 + scg],           kn + rr*2048 + wave*512);
                async_cp16(&Vb[(size_t)(rr*32 + srow)*2048 + scg], vn + rr*2048 + wave*512);
            }
        }

        // compute on current tile: per k-slice ks (32 keys), kj pair -> QK^T
        // -> exp2 -> pack -> permlane exchange -> PV.
        #pragma unroll
        for (int ks=0;ks<2;ks++){
            unsigned Ud[2][2], Wd[2][2];   // [m][dword]; U: kj=2ks, W: kj=2ks+1
            #pragma unroll
            for (int aa=0;aa<2;aa++){
                int kj = ks*2 + aa;
                // row = kj*16+cc; true granule g read at position g^(cc&7)
                f16x8 k0 = *(const f16x8*)&kc[(kj*16+cc)*64 + ((q4    ^(cc&7))*8)];
                f16x8 k1 = *(const f16x8*)&kc[(kj*16+cc)*64 + (((4+q4)^(cc&7))*8)];
                #pragma unroll
                for (int m=0;m<2;m++){
                    f32x4 z = {};
                    f32x4 s = MFMA16(k0, qf[m][0], z);
                    s = MFMA16(k1, qf[m][1], s);
                    float p0 = __builtin_amdgcn_exp2f(s[0]);
                    float p1 = __builtin_amdgcn_exp2f(s[1]);
                    float p2 = __builtin_amdgcn_exp2f(s[2]);
                    float p3 = __builtin_amdgcn_exp2f(s[3]);
                    lsum[m] += (p0 + p1) + (p2 + p3);
                    unsigned d0 = __builtin_bit_cast(unsigned, pk(p0, p1));
                    unsigned d1 = __builtin_bit_cast(unsigned, pk(p2, p3));
                    if (aa == 0) { Ud[m][0] = d0; Ud[m][1] = d1; }
                    else         { Wd[m][0] = d0; Wd[m][1] = d1; }
                }
            }
            // A-frag: lane (cc,q4) needs keys 32ks+8q4+{0..7} of q-row cc.
            f16x8 pa[2];
            #pragma unroll
            for (int m=0;m<2;m++){
                u32x2 x0 = __builtin_amdgcn_permlane32_swap(Ud[m][0], Wd[m][0], false, false);
                u32x2 r02 = __builtin_amdgcn_permlane16_swap(x0[0], x0[1], false, false);
                u32x2 x1 = __builtin_amdgcn_permlane32_swap(Ud[m][1], Wd[m][1], false, false);
                u32x2 r13 = __builtin_amdgcn_permlane16_swap(x1[0], x1[1], false, false);
                u32x4 pw;
                pw[0] = r02[0]; pw[1] = r13[0]; pw[2] = r02[1]; pw[3] = r13[1];
                pa[m] = __builtin_bit_cast(f16x8, pw);
            }
            #pragma unroll
            for (int v=0;v<4;v++){
                // row = v*16+cc (dk); true granule ks*4+q4 (keys 32ks+8q4+..)
                f16x8 vf = *(const f16x8*)&vc[(v*16+cc)*64 + (((ks*4+q4)^(cc&7))*8)];
                o[0][v] = MFMA16(pa[0], vf, o[0][v]);
                o[1][v] = MFMA16(pa[1], vf, o[1][v]);
            }
        }

        asm volatile("s_waitcnt vmcnt(0)" ::: "memory");
        __syncthreads();   // next tile staged + all reads of cur done
        __builtin_amdgcn_sched_barrier(0);
    }

    // row sums: lane holds partial for q-row cc; reduce over the 4 q4-lanes,
    // then transpose cc -> (q4*4+r) through a tiny LDS buffer.
    #pragma unroll
    for (int m=0;m<2;m++){
        lsum[m] += __shfl_xor(lsum[m], 16, 64);
        lsum[m] += __shfl_xor(lsum[m], 32, 64);
    }
    if (q4 == 0) {
        sL[wave*32 + cc]      = lsum[0];
        sL[wave*32 + 16 + cc] = lsum[1];
    }
    __syncthreads();

    int b = bh >> 4, h = bh & 15;
    #pragma unroll
    for (int m=0;m<2;m++)
      #pragma unroll
      for (int r=0;r<4;r++){
        float inv = 1.f / sL[wave*32 + m*16 + q4*4 + r];
        int s = qbase + m*16 + q4*4 + r;
        #pragma unroll
        for (int v=0;v<4;v++){
            float val = o[m][v][r]*inv;
            int dk = v*16 + cc;
            Ctx[((size_t)(b*2048+s)*16 + h)*64 + dk] = (_Float16)val;  // (B,S,H,DK)
        }
      }
}

extern "C" void kernel_launch(void* const* d_in, const int* in_sizes, int n_in,
                              void* d_out, int out_size, void* d_ws, size_t ws_size,
                              hipStream_t stream)
{
    const float* q  = (const float*)d_in[0];
    const float* Wq = (const float*)d_in[1];
    const float* bq = (const float*)d_in[2];
    const float* Wk = (const float*)d_in[3];
    const float* bk = (const float*)d_in[4];
    const float* Wv = (const float*)d_in[5];
    const float* bv = (const float*)d_in[6];
    const float* Wo = (const float*)d_in[7];
    const float* bo = (const float*)d_in[8];
    float* out = (float*)d_out;

    _Float16* ws  = (_Float16*)d_ws;
    _Float16* wt  = ws;                   // 4 x 1M fp16 = 8MB
    _Float16* Xh  = ws + 4194304;         // 16MB
    _Float16* Q   = ws + 12582912;
    _Float16* K   = ws + 20971520;
    _Float16* Vt  = ws + 29360128;        // end 37748736 el = 75.5MB
    _Float16* Ctx = Xh;                   // X dead after gemm_qkv

    prep_weights<<<dim3(1024,4), 256, 0, stream>>>(Wq, Wk, Wv, Wo, wt);
    cvt_x<<<dim3(8192), 256, 0, stream>>>(q, Xh);
    gemm_qkv<<<dim3(1536), 256, 0, stream>>>(Xh, wt, bq, bk, bv, Q, K, Vt);
    attn<<<dim3(1024), 256, 0, stream>>>(Q, K, Vt, Ctx);
    gemm_out<<<dim3(512), 256, 0, stream>>>(Ctx, wt, bo, out);
}

// Round 9
// 292.877 us; speedup vs baseline: 1.0710x; 1.0090x over previous
//
#include <hip/hip_runtime.h>
#include <hip/hip_bf16.h>
#include <math.h>

// MultiheadAttention: B=4,S=2048,E=1024,H=16,DK=64, fp32 in/out.
// All-fp16 MFMA; static-max softmax in exp2 domain.
// GEMMs v5: R4's fine-phase triple-buffered pipeline (2 phases/K-tile,
// counted vmcnt(6), setprio) RE-TESTED with R5's L2 supertile mapping
// (4m x 4n window = 3MB < 4MB L2). R3/R4's pipeline nulls were measured
// under the L2-thrashing mapping (fixed in R5) -> confounded.
// attn v7 = R8's race-free double-buffered DMA body + unroll-2 kt loop,
// precomputed LDS offsets, strength-reduced global pointers (VALU cut:
// R8 showed VALUBusy 51% > MfmaUtil 32% with only 52 VGPRs allocated).
// NEVER cap attn at 128 regs (R1/R6 spill disasters).

typedef _Float16 f16x8 __attribute__((ext_vector_type(8)));
typedef _Float16 f16x4 __attribute__((ext_vector_type(4)));
typedef _Float16 f16x2 __attribute__((ext_vector_type(2)));
typedef float    f32x4 __attribute__((ext_vector_type(4)));
typedef unsigned int u32x2 __attribute__((ext_vector_type(2)));
typedef unsigned int u32x4 __attribute__((ext_vector_type(4)));

#define MFMA16(a,b,c) __builtin_amdgcn_mfma_f32_16x16x32_f16(a,b,c,0,0,0)

__device__ __forceinline__ void async_cp16(const _Float16* g, _Float16* l) {
    __builtin_amdgcn_global_load_lds(
        (const __attribute__((address_space(1))) unsigned int*)g,
        (__attribute__((address_space(3))) unsigned int*)l,
        16, 0, 0);
}

__device__ __forceinline__ f16x2 pk(float a, float b) {
    return __builtin_bit_cast(f16x2, __builtin_amdgcn_cvt_pkrtz(a, b));
}

// ---- weight transpose (coalesced, via LDS) + cvt: W (K x N) -> WT fp16 (N x K) ----
__global__ void __launch_bounds__(256) prep_weights(
    const float* __restrict__ Wq, const float* __restrict__ Wk,
    const float* __restrict__ Wv, const float* __restrict__ Wo,
    _Float16* __restrict__ wt)
{
    __shared__ float tile[32][33];
    int mat = blockIdx.y;
    const float* W = (mat==0)?Wq:(mat==1)?Wk:(mat==2)?Wv:Wo;
    _Float16* WT = wt + (size_t)mat*1048576;
    int t = blockIdx.x;              // 0..1023
    int kb = (t & 31) * 32;
    int nb = (t >> 5) * 32;
    int tx = threadIdx.x & 31, ty = threadIdx.x >> 5;   // ty 0..7
    #pragma unroll
    for (int r = 0; r < 4; ++r) {
        int row = ty + r*8;
        tile[row][tx] = W[(size_t)(kb+row)*1024 + nb + tx];
    }
    __syncthreads();
    #pragma unroll
    for (int r = 0; r < 4; ++r) {
        int row = ty + r*8;
        WT[(size_t)(nb+row)*1024 + kb + tx] = (_Float16)tile[tx][row];
    }
}

// ---- X (8192x1024 fp32) -> fp16 ----
__global__ void __launch_bounds__(256) cvt_x(
    const float* __restrict__ X, _Float16* __restrict__ Xh)
{
    int i = (blockIdx.x*256 + threadIdx.x)*4;
    f32x4 x = *(const f32x4*)&X[i];
    f16x4 h;
    #pragma unroll
    for (int k=0;k<4;k++) h[k] = (_Float16)x[k];
    *(f16x4*)&Xh[i] = h;
}

// ---- GEMM staging: A tile 128x64 (2 load-rounds), B tile 256x64 (4 rounds).
// Dest linear granules; source granule pre-swizzled g^(row&7) so fragment
// reads lds[row*64 + ((ks*4+q4)^(row&7))*8] are conflict-free (measured 0).
__device__ __forceinline__ void stage3a(
    const _Float16* __restrict__ Ag, const _Float16* __restrict__ Bg, int kb,
    _Float16* sAb, _Float16* sBb, int wave, int lane)
{
    #pragma unroll
    for (int j = 0; j < 2; ++j) {
        int d   = j*512 + wave*64 + lane;
        int row = d >> 3;
        int sg  = (d & 7) ^ (row & 7);
        async_cp16(&Ag[(size_t)row*1024 + kb + sg*8], sAb + (j*512 + wave*64)*8);
    }
    {
        int d   = wave*64 + lane;
        int row = d >> 3;
        int sg  = (d & 7) ^ (row & 7);
        async_cp16(&Bg[(size_t)row*1024 + kb + sg*8], sBb + (wave*64)*8);
    }
}
__device__ __forceinline__ void stage3b(
    const _Float16* __restrict__ Bg, int kb, _Float16* sBb, int wave, int lane)
{
    #pragma unroll
    for (int j = 1; j < 4; ++j) {
        int d   = j*512 + wave*64 + lane;
        int row = d >> 3;
        int sg  = (d & 7) ^ (row & 7);
        async_cp16(&Bg[(size_t)row*1024 + kb + sg*8], sBb + (j*512 + wave*64)*8);
    }
}

// K-loop: 16 tiles, buffers rotate over 3; tile t computes from pA0/pB0 while
// tile t+2 streams into pA2/pB2 (buf of dead tile t-1 -> race-free). Per tile
// two fine phases; one counted vmcnt per tile at the boundary (6 = tile t+2's
// loads in flight; tiles 14/15 drain with 0).
#define GEMM_PIPE_LOOP()                                                       \
    stage3a(Ag, Bg, 0,  pA0, pB0, wave, lane);                                 \
    stage3b(Bg, 0,  pB0, wave, lane);                                          \
    stage3a(Ag, Bg, 64, pA1, pB1, wave, lane);                                 \
    stage3b(Bg, 64, pB1, wave, lane);                                          \
    asm volatile("s_waitcnt vmcnt(6)" ::: "memory");                           \
    __builtin_amdgcn_s_barrier();                                              \
    __builtin_amdgcn_sched_barrier(0);                                         \
    for (int t = 0; t < 16; ++t) {                                             \
        /* ---- phase 0 (ks=0): reads + stage3a(t+2) + MFMA ---- */            \
        f16x8 af0[4], bf0[4];                                                  \
        _Pragma("unroll")                                                      \
        for (int i = 0; i < 4; ++i)                                            \
            af0[i] = *(const f16x8*)&pA0[(wr*64+i*16+cc)*64 +                  \
                                         ((q4^(cc&7))*8)];                     \
        _Pragma("unroll")                                                      \
        for (int j = 0; j < 4; ++j)                                            \
            bf0[j] = *(const f16x8*)&pB0[(wc*64+j*16+cc)*64 +                  \
                                         ((q4^(cc&7))*8)];                     \
        if (t < 14) stage3a(Ag, Bg, (t+2)*64, pA2, pB2, wave, lane);           \
        __builtin_amdgcn_sched_barrier(0);                                     \
        __builtin_amdgcn_s_barrier();                                          \
        asm volatile("s_waitcnt lgkmcnt(0)" ::: "memory");                     \
        __builtin_amdgcn_sched_barrier(0);                                     \
        __builtin_amdgcn_s_setprio(1);                                         \
        _Pragma("unroll")                                                      \
        for (int i = 0; i < 4; ++i)                                            \
            _Pragma("unroll")                                                  \
            for (int j = 0; j < 4; ++j)                                        \
                acc[i][j] = MFMA16(af0[i], bf0[j], acc[i][j]);                 \
        __builtin_amdgcn_s_setprio(0);                                         \
        __builtin_amdgcn_sched_barrier(0);                                     \
        __builtin_amdgcn_s_barrier();                                          \
        /* ---- phase 1 (ks=1): reads + stage3b(t+2) + MFMA + vmcnt ---- */    \
        f16x8 af1[4], bf1[4];                                                  \
        _Pragma("unroll")                                                      \
        for (int i = 0; i < 4; ++i)                                            \
            af1[i] = *(const f16x8*)&pA0[(wr*64+i*16+cc)*64 +                  \
                                         (((4+q4)^(cc&7))*8)];                 \
        _Pragma("unroll")                                                      \
        for (int j = 0; j < 4; ++j)                                            \
            bf1[j] = *(const f16x8*)&pB0[(wc*64+j*16+cc)*64 +                  \
                                         (((4+q4)^(cc&7))*8)];                 \
        if (t < 14) stage3b(Bg, (t+2)*64, pB2, wave, lane);                    \
        __builtin_amdgcn_sched_barrier(0);                                     \
        __builtin_amdgcn_s_barrier();                                          \
        asm volatile("s_waitcnt lgkmcnt(0)" ::: "memory");                     \
        __builtin_amdgcn_sched_barrier(0);                                     \
        __builtin_amdgcn_s_setprio(1);                                         \
        _Pragma("unroll")                                                      \
        for (int i = 0; i < 4; ++i)                                            \
            _Pragma("unroll")                                                  \
            for (int j = 0; j < 4; ++j)                                        \
                acc[i][j] = MFMA16(af1[i], bf1[j], acc[i][j]);                 \
        __builtin_amdgcn_s_setprio(0);                                         \
        if (t < 14) asm volatile("s_waitcnt vmcnt(6)" ::: "memory");           \
        else        asm volatile("s_waitcnt vmcnt(0)" ::: "memory");           \
        __builtin_amdgcn_sched_barrier(0);                                     \
        __builtin_amdgcn_s_barrier();                                          \
        _Float16* tA = pA0; pA0 = pA1; pA1 = pA2; pA2 = tA;                    \
        _Float16* tB = pB0; pB0 = pB1; pB1 = pB2; pB2 = tB;                    \
    }

// ---- fused QKV projection GEMM: C = X * W^T + b, 128x256 tile ----
// grid 768: xcd = id&7; per-XCD lid walks 4m x 4n supertiles:
//   lid = (ng:3)(mq:2)(m_lo:4)(nb:4) -> 16-block windows share
//   4 A-panels (256KB) + 4 B-panels (512KB) = 3MB < 4MB L2.
__global__ void __launch_bounds__(512) gemm_qkv(
    const _Float16* __restrict__ Xh, const _Float16* __restrict__ wt,
    const float* __restrict__ bq, const float* __restrict__ bk, const float* __restrict__ bv,
    _Float16* __restrict__ Q, _Float16* __restrict__ K, _Float16* __restrict__ Vt)
{
    __shared__ __align__(16) _Float16 sA[3][8192];    // 3 x 128x64
    __shared__ __align__(16) _Float16 sB[3][16384];   // 3 x 256x64

    const int id = blockIdx.x;        // 0..767
    const int xcd = id & 7;
    const int lid = id >> 3;          // 0..95
    const int ng  = lid >> 5;         // 0..2
    const int rem = lid & 31;
    const int mq  = rem >> 4;         // 0..1
    const int r2  = rem & 15;
    const int m_lo = r2 >> 2;         // 0..3
    const int nb   = r2 & 3;          // 0..3
    const int mblk = (mq*4 + m_lo)*8 + xcd;   // 0..63
    const int nblk = ng*4 + nb;               // 0..11

    const int tid = threadIdx.x;
    const int wave = tid >> 6, lane = tid & 63;
    const int wr = wave & 1, wc = wave >> 1;  // 2M x 4N
    const int q4 = lane >> 4, cc = lane & 15;

    const int mat = nblk >> 2;               // 0=q 1=k 2=v
    const int colbase = (nblk & 3) * 256;
    const _Float16* Bg = wt + (size_t)mat*1048576 + (size_t)colbase*1024;
    const _Float16* Ag = Xh + (size_t)mblk*131072;

    _Float16 *pA0 = &sA[0][0], *pA1 = &sA[1][0], *pA2 = &sA[2][0];
    _Float16 *pB0 = &sB[0][0], *pB1 = &sB[1][0], *pB2 = &sB[2][0];

    f32x4 acc[4][4] = {};

    GEMM_PIPE_LOOP()

    const float* bias = (mat==0)?bq:(mat==1)?bk:bv;
    const float QSCALE = 0.125f * 1.44269504f;
    #pragma unroll
    for (int i=0;i<4;i++)
      #pragma unroll
      for (int j=0;j<4;j++)
        #pragma unroll
        for (int r=0;r<4;r++){
            int m = mblk*128 + wr*64 + i*16 + q4*4 + r;
            int ncol = colbase + wc*64 + j*16 + cc;     // 0..1023 in matrix
            float val = acc[i][j][r] + bias[ncol];
            int b = m >> 11, s = m & 2047;
            int h = ncol >> 6, dk = ncol & 63;
            if (mat == 2) {
                Vt[((size_t)(b*16+h)*64 + dk)*2048 + s] = (_Float16)val;  // V^T: (B,H,DK,S)
            } else {
                size_t qi = ((size_t)(b*16+h)*2048 + s)*64 + dk;          // (B,H,S,DK)
                if (mat == 0) Q[qi] = (_Float16)(val * QSCALE);
                else          K[qi] = (_Float16)val;
            }
        }
}

// ---- output projection: out = ctx * Wo^T + bo, 128x256 tile ----
// grid 256 = one exact resident round; per-XCD 4m x 4n supertile (3MB).
__global__ void __launch_bounds__(512) gemm_out(
    const _Float16* __restrict__ Ctx, const _Float16* __restrict__ wt,
    const float* __restrict__ bo,
    float* __restrict__ out)
{
    __shared__ __align__(16) _Float16 sA[3][8192];
    __shared__ __align__(16) _Float16 sB[3][16384];

    const int id = blockIdx.x;        // 0..255
    const int xcd = id & 7;
    const int lid = id >> 3;          // 0..31
    const int mq  = lid >> 4;         // 0..1
    const int r2  = lid & 15;
    const int m_lo = r2 >> 2;         // 0..3
    const int nblk = r2 & 3;          // 0..3
    const int mblk = (mq*4 + m_lo)*8 + xcd;   // 0..63

    const int tid = threadIdx.x;
    const int wave = tid >> 6, lane = tid & 63;
    const int wr = wave & 1, wc = wave >> 1;
    const int q4 = lane >> 4, cc = lane & 15;

    const _Float16* Bg = wt + (size_t)3*1048576 + (size_t)nblk*256*1024;
    const _Float16* Ag = Ctx + (size_t)mblk*131072;

    _Float16 *pA0 = &sA[0][0], *pA1 = &sA[1][0], *pA2 = &sA[2][0];
    _Float16 *pB0 = &sB[0][0], *pB1 = &sB[1][0], *pB2 = &sB[2][0];

    f32x4 acc[4][4] = {};

    GEMM_PIPE_LOOP()

    #pragma unroll
    for (int i=0;i<4;i++)
      #pragma unroll
      for (int j=0;j<4;j++)
        #pragma unroll
        for (int r=0;r<4;r++){
            int m = mblk*128 + wr*64 + i*16 + q4*4 + r;
            int n = nblk*256 + wc*64 + j*16 + cc;
            out[(size_t)m*1024 + n] = acc[i][j][r] + bo[n];
        }
}

// ---- flash attention, static-max softmax: 128 q-rows/block, 64-key tiles ----
// 1-D grid 1024: XCD = id%8; each XCD runs one head's 16 q-chunks before the
// next head (512 KB K/V live per XCD L2, fetched once).
// Double-buffered K/V tiles via global_load_lds with source-granule XOR
// swizzle; per tile: issue next-tile DMA -> compute -> vmcnt(0) -> barrier.
// v7: kt loop unrolled x2 (static buffer parity), all LDS fragment offsets
// and staging offsets precomputed, next-tile global pointers strength-
// reduced (R8: VALUBusy 51% with 52 VGPR -> compiler recomputed addresses).
__global__ void __launch_bounds__(256,3) attn(
    const _Float16* __restrict__ Qg, const _Float16* __restrict__ Kg,
    const _Float16* __restrict__ Vg,
    _Float16* __restrict__ Ctx)
{
    __shared__ __align__(16) _Float16 sK[2][4096];   // 64 keys x 64 dims
    __shared__ __align__(16) _Float16 sV[2][4096];   // 64 dims x 64 keys
    __shared__ float sL[128];

    const int id = blockIdx.x;
    const int xcd = id & 7;
    const int t2 = id >> 3;           // 0..127
    const int qc = t2 & 15;
    const int bh = (t2 >> 4) * 8 + xcd;

    const int tid = threadIdx.x;
    const int wave = tid >> 6, lane = tid & 63;
    const int q4 = lane >> 4, cc = lane & 15;

    const size_t hoff = (size_t)bh * 131072;   // 2048*64
    const _Float16* Qp = Qg + hoff;
    const _Float16* Kp = Kg + hoff;
    const _Float16* Vp = Vg + hoff;

    const int qbase = qc*128 + wave*32;

    f16x8 qf[2][2];
    #pragma unroll
    for (int m=0;m<2;m++)
      #pragma unroll
      for (int ks=0;ks<2;ks++)
        qf[m][ks] = *(const f16x8*)&Qp[(qbase+m*16+cc)*64 + ks*32 + q4*8];

    f32x4 o[2][4] = {};
    float lsum[2] = {0.f, 0.f};

    // ---- precomputed loop-invariant offsets (element units) ----
    // staging: row = rr*32 + (tid>>3); source granule (tid&7)^(row&7) lands
    // at dest position tid&7 (linear dest = base + lane*16B).
    const int srow = tid >> 3;
    const int scg  = ((tid & 7) ^ ((tid >> 3) & 7)) * 8;
    int kofs[2], vofs[2], dofs[2];
    #pragma unroll
    for (int rr = 0; rr < 2; ++rr) {
        kofs[rr] = (rr*32 + srow)*64 + scg;
        vofs[rr] = (rr*32 + srow)*2048 + scg;
        dofs[rr] = rr*2048 + wave*512;
    }
    // fragment reads: K row kj*16+cc (row&7 == cc&7), granules q4 / 4+q4;
    // V row v*16+cc, granule ks*4+q4.
    int okA[4], okB[4];
    #pragma unroll
    for (int kj=0;kj<4;kj++){
        okA[kj] = (kj*16+cc)*64 + ((q4    ^(cc&7))*8);
        okB[kj] = (kj*16+cc)*64 + (((4+q4)^(cc&7))*8);
    }
    int ov[2][4];
    #pragma unroll
    for (int ks=0;ks<2;ks++)
      #pragma unroll
      for (int v=0;v<4;v++)
        ov[ks][v] = (v*16+cc)*64 + (((ks*4+q4)^(cc&7))*8);

    // prologue: stage tile 0 into buffer 0
    #pragma unroll
    for (int rr = 0; rr < 2; ++rr) {
        async_cp16(Kp + kofs[rr], &sK[0][dofs[rr]]);
        async_cp16(Vp + vofs[rr], &sV[0][dofs[rr]]);
    }
    asm volatile("s_waitcnt vmcnt(0)" ::: "memory");
    __syncthreads();
    __builtin_amdgcn_sched_barrier(0);

    const _Float16* KbN = Kp + 4096;   // next-tile bases, strength-reduced
    const _Float16* VbN = Vp + 64;

    #pragma unroll 2
    for (int kt = 0; kt < 32; ++kt) {
        const int cur = kt & 1;
        const _Float16* kc = &sK[cur][0];
        const _Float16* vc = &sV[cur][0];

        // issue next tile's DMA into the OTHER buffer (hidden under compute)
        if (kt < 31) {
            _Float16* kn = &sK[cur ^ 1][0];
            _Float16* vn = &sV[cur ^ 1][0];
            #pragma unroll
            for (int rr = 0; rr < 2; ++rr) {
                async_cp16(KbN + kofs[rr], kn + dofs[rr]);
                async_cp16(VbN + vofs[rr], vn + dofs[rr]);
            }
        }

        // compute on current tile: per k-slice ks (32 keys), kj pair -> QK^T
        // -> exp2 -> pack -> permlane exchange -> PV.
        #pragma unroll
        for (int ks=0;ks<2;ks++){
            unsigned Ud[2][2], Wd[2][2];   // [m][dword]; U: kj=2ks, W: kj=2ks+1
            #pragma unroll
            for (int aa=0;aa<2;aa++){
                int kj = ks*2 + aa;
                f16x8 k0 = *(const f16x8*)&kc[okA[kj]];
                f16x8 k1 = *(const f16x8*)&kc[okB[kj]];
                #pragma unroll
                for (int m=0;m<2;m++){
                    f32x4 z = {};
                    f32x4 s = MFMA16(k0, qf[m][0], z);
                    s = MFMA16(k1, qf[m][1], s);
                    float p0 = __builtin_amdgcn_exp2f(s[0]);
                    float p1 = __builtin_amdgcn_exp2f(s[1]);
                    float p2 = __builtin_amdgcn_exp2f(s[2]);
                    float p3 = __builtin_amdgcn_exp2f(s[3]);
                    lsum[m] += (p0 + p1) + (p2 + p3);
                    unsigned d0 = __builtin_bit_cast(unsigned, pk(p0, p1));
                    unsigned d1 = __builtin_bit_cast(unsigned, pk(p2, p3));
                    if (aa == 0) { Ud[m][0] = d0; Ud[m][1] = d1; }
                    else         { Wd[m][0] = d0; Wd[m][1] = d1; }
                }
            }
            // A-frag: lane (cc,q4) needs keys 32ks+8q4+{0..7} of q-row cc.
            f16x8 pa[2];
            #pragma unroll
            for (int m=0;m<2;m++){
                u32x2 x0 = __builtin_amdgcn_permlane32_swap(Ud[m][0], Wd[m][0], false, false);
                u32x2 r02 = __builtin_amdgcn_permlane16_swap(x0[0], x0[1], false, false);
                u32x2 x1 = __builtin_amdgcn_permlane32_swap(Ud[m][1], Wd[m][1], false, false);
                u32x2 r13 = __builtin_amdgcn_permlane16_swap(x1[0], x1[1], false, false);
                u32x4 pw;
                pw[0] = r02[0]; pw[1] = r13[0]; pw[2] = r02[1]; pw[3] = r13[1];
                pa[m] = __builtin_bit_cast(f16x8, pw);
            }
            #pragma unroll
            for (int v=0;v<4;v++){
                f16x8 vf = *(const f16x8*)&vc[ov[ks][v]];
                o[0][v] = MFMA16(pa[0], vf, o[0][v]);
                o[1][v] = MFMA16(pa[1], vf, o[1][v]);
            }
        }

        KbN += 4096;
        VbN += 64;
        asm volatile("s_waitcnt vmcnt(0)" ::: "memory");
        __syncthreads();   // next tile staged + all reads of cur done
        __builtin_amdgcn_sched_barrier(0);
    }

    // row sums: lane holds partial for q-row cc; reduce over the 4 q4-lanes,
    // then transpose cc -> (q4*4+r) through a tiny LDS buffer.
    #pragma unroll
    for (int m=0;m<2;m++){
        lsum[m] += __shfl_xor(lsum[m], 16, 64);
        lsum[m] += __shfl_xor(lsum[m], 32, 64);
    }
    if (q4 == 0) {
        sL[wave*32 + cc]      = lsum[0];
        sL[wave*32 + 16 + cc] = lsum[1];
    }
    __syncthreads();

    int b = bh >> 4, h = bh & 15;
    #pragma unroll
    for (int m=0;m<2;m++)
      #pragma unroll
      for (int r=0;r<4;r++){
        float inv = 1.f / sL[wave*32 + m*16 + q4*4 + r];
        int s = qbase + m*16 + q4*4 + r;
        #pragma unroll
        for (int v=0;v<4;v++){
            float val = o[m][v][r]*inv;
            int dk = v*16 + cc;
            Ctx[((size_t)(b*2048+s)*16 + h)*64 + dk] = (_Float16)val;  // (B,S,H,DK)
        }
      }
}

extern "C" void kernel_launch(void* const* d_in, const int* in_sizes, int n_in,
                              void* d_out, int out_size, void* d_ws, size_t ws_size,
                              hipStream_t stream)
{
    const float* q  = (const float*)d_in[0];
    const float* Wq = (const float*)d_in[1];
    const float* bq = (const float*)d_in[2];
    const float* Wk = (const float*)d_in[3];
    const float* bk = (const float*)d_in[4];
    const float* Wv = (const float*)d_in[5];
    const float* bv = (const float*)d_in[6];
    const float* Wo = (const float*)d_in[7];
    const float* bo = (const float*)d_in[8];
    float* out = (float*)d_out;

    _Float16* ws  = (_Float16*)d_ws;
    _Float16* wt  = ws;                   // 4 x 1M fp16 = 8MB
    _Float16* Xh  = ws + 4194304;         // 16MB
    _Float16* Q   = ws + 12582912;
    _Float16* K   = ws + 20971520;
    _Float16* Vt  = ws + 29360128;        // end 37748736 el = 75.5MB
    _Float16* Ctx = Xh;                   // X dead after gemm_qkv

    prep_weights<<<dim3(1024,4), 256, 0, stream>>>(Wq, Wk, Wv, Wo, wt);
    cvt_x<<<dim3(8192), 256, 0, stream>>>(q, Xh);
    gemm_qkv<<<dim3(768), 512, 0, stream>>>(Xh, wt, bq, bk, bv, Q, K, Vt);
    attn<<<dim3(1024), 256, 0, stream>>>(Q, K, Vt, Ctx);
    gemm_out<<<dim3(256), 512, 0, stream>>>(Ctx, wt, bo, out);
}

// Round 10
// 279.497 us; speedup vs baseline: 1.1223x; 1.0479x over previous
//
#include <hip/hip_runtime.h>
#include <hip/hip_bf16.h>
#include <math.h>

// MultiheadAttention: B=4,S=2048,E=1024,H=16,DK=64, fp32 in/out.
// All-fp16 MFMA; static-max softmax in exp2 domain.
// GEMMs v5 (R9): fine-phase triple-buffered pipeline + L2 supertile walk.
// attn v8 = R9 body (double-buffered DMA, precomputed offsets, unroll-2)
// with launch_bounds(256,4): R9's (256,3) ran grid 1024 as 768 + 256-tail
// (measured occupancy 23.5% == time-weighted 37.5/12.5 mix); 4 blocks/CU
// gives ONE exact resident round. Register check: R9 allocated 72 arch
// + ~32 acc = ~104 <= 128 cap, so (256,4) does not spill THIS body
// (R1/R6 spills were higher-pressure bodies; kill-switch = WRITE_SIZE).

typedef _Float16 f16x8 __attribute__((ext_vector_type(8)));
typedef _Float16 f16x4 __attribute__((ext_vector_type(4)));
typedef _Float16 f16x2 __attribute__((ext_vector_type(2)));
typedef float    f32x4 __attribute__((ext_vector_type(4)));
typedef unsigned int u32x2 __attribute__((ext_vector_type(2)));
typedef unsigned int u32x4 __attribute__((ext_vector_type(4)));

#define MFMA16(a,b,c) __builtin_amdgcn_mfma_f32_16x16x32_f16(a,b,c,0,0,0)

__device__ __forceinline__ void async_cp16(const _Float16* g, _Float16* l) {
    __builtin_amdgcn_global_load_lds(
        (const __attribute__((address_space(1))) unsigned int*)g,
        (__attribute__((address_space(3))) unsigned int*)l,
        16, 0, 0);
}

__device__ __forceinline__ f16x2 pk(float a, float b) {
    return __builtin_bit_cast(f16x2, __builtin_amdgcn_cvt_pkrtz(a, b));
}

// ---- weight transpose (coalesced, via LDS) + cvt: W (K x N) -> WT fp16 (N x K) ----
__global__ void __launch_bounds__(256) prep_weights(
    const float* __restrict__ Wq, const float* __restrict__ Wk,
    const float* __restrict__ Wv, const float* __restrict__ Wo,
    _Float16* __restrict__ wt)
{
    __shared__ float tile[32][33];
    int mat = blockIdx.y;
    const float* W = (mat==0)?Wq:(mat==1)?Wk:(mat==2)?Wv:Wo;
    _Float16* WT = wt + (size_t)mat*1048576;
    int t = blockIdx.x;              // 0..1023
    int kb = (t & 31) * 32;
    int nb = (t >> 5) * 32;
    int tx = threadIdx.x & 31, ty = threadIdx.x >> 5;   // ty 0..7
    #pragma unroll
    for (int r = 0; r < 4; ++r) {
        int row = ty + r*8;
        tile[row][tx] = W[(size_t)(kb+row)*1024 + nb + tx];
    }
    __syncthreads();
    #pragma unroll
    for (int r = 0; r < 4; ++r) {
        int row = ty + r*8;
        WT[(size_t)(nb+row)*1024 + kb + tx] = (_Float16)tile[tx][row];
    }
}

// ---- X (8192x1024 fp32) -> fp16 ----
__global__ void __launch_bounds__(256) cvt_x(
    const float* __restrict__ X, _Float16* __restrict__ Xh)
{
    int i = (blockIdx.x*256 + threadIdx.x)*4;
    f32x4 x = *(const f32x4*)&X[i];
    f16x4 h;
    #pragma unroll
    for (int k=0;k<4;k++) h[k] = (_Float16)x[k];
    *(f16x4*)&Xh[i] = h;
}

// ---- GEMM staging: A tile 128x64 (2 load-rounds), B tile 256x64 (4 rounds).
__device__ __forceinline__ void stage3a(
    const _Float16* __restrict__ Ag, const _Float16* __restrict__ Bg, int kb,
    _Float16* sAb, _Float16* sBb, int wave, int lane)
{
    #pragma unroll
    for (int j = 0; j < 2; ++j) {
        int d   = j*512 + wave*64 + lane;
        int row = d >> 3;
        int sg  = (d & 7) ^ (row & 7);
        async_cp16(&Ag[(size_t)row*1024 + kb + sg*8], sAb + (j*512 + wave*64)*8);
    }
    {
        int d   = wave*64 + lane;
        int row = d >> 3;
        int sg  = (d & 7) ^ (row & 7);
        async_cp16(&Bg[(size_t)row*1024 + kb + sg*8], sBb + (wave*64)*8);
    }
}
__device__ __forceinline__ void stage3b(
    const _Float16* __restrict__ Bg, int kb, _Float16* sBb, int wave, int lane)
{
    #pragma unroll
    for (int j = 1; j < 4; ++j) {
        int d   = j*512 + wave*64 + lane;
        int row = d >> 3;
        int sg  = (d & 7) ^ (row & 7);
        async_cp16(&Bg[(size_t)row*1024 + kb + sg*8], sBb + (j*512 + wave*64)*8);
    }
}

// K-loop: 16 tiles, buffers rotate over 3; tile t computes from pA0/pB0 while
// tile t+2 streams into pA2/pB2. Per tile two fine phases; counted vmcnt(6).
#define GEMM_PIPE_LOOP()                                                       \
    stage3a(Ag, Bg, 0,  pA0, pB0, wave, lane);                                 \
    stage3b(Bg, 0,  pB0, wave, lane);                                          \
    stage3a(Ag, Bg, 64, pA1, pB1, wave, lane);                                 \
    stage3b(Bg, 64, pB1, wave, lane);                                          \
    asm volatile("s_waitcnt vmcnt(6)" ::: "memory");                           \
    __builtin_amdgcn_s_barrier();                                              \
    __builtin_amdgcn_sched_barrier(0);                                         \
    for (int t = 0; t < 16; ++t) {                                             \
        f16x8 af0[4], bf0[4];                                                  \
        _Pragma("unroll")                                                      \
        for (int i = 0; i < 4; ++i)                                            \
            af0[i] = *(const f16x8*)&pA0[(wr*64+i*16+cc)*64 +                  \
                                         ((q4^(cc&7))*8)];                     \
        _Pragma("unroll")                                                      \
        for (int j = 0; j < 4; ++j)                                            \
            bf0[j] = *(const f16x8*)&pB0[(wc*64+j*16+cc)*64 +                  \
                                         ((q4^(cc&7))*8)];                     \
        if (t < 14) stage3a(Ag, Bg, (t+2)*64, pA2, pB2, wave, lane);           \
        __builtin_amdgcn_sched_barrier(0);                                     \
        __builtin_amdgcn_s_barrier();                                          \
        asm volatile("s_waitcnt lgkmcnt(0)" ::: "memory");                     \
        __builtin_amdgcn_sched_barrier(0);                                     \
        __builtin_amdgcn_s_setprio(1);                                         \
        _Pragma("unroll")                                                      \
        for (int i = 0; i < 4; ++i)                                            \
            _Pragma("unroll")                                                  \
            for (int j = 0; j < 4; ++j)                                        \
                acc[i][j] = MFMA16(af0[i], bf0[j], acc[i][j]);                 \
        __builtin_amdgcn_s_setprio(0);                                         \
        __builtin_amdgcn_sched_barrier(0);                                     \
        __builtin_amdgcn_s_barrier();                                          \
        f16x8 af1[4], bf1[4];                                                  \
        _Pragma("unroll")                                                      \
        for (int i = 0; i < 4; ++i)                                            \
            af1[i] = *(const f16x8*)&pA0[(wr*64+i*16+cc)*64 +                  \
                                         (((4+q4)^(cc&7))*8)];                 \
        _Pragma("unroll")                                                      \
        for (int j = 0; j < 4; ++j)                                            \
            bf1[j] = *(const f16x8*)&pB0[(wc*64+j*16+cc)*64 +                  \
                                         (((4+q4)^(cc&7))*8)];                 \
        if (t < 14) stage3b(Bg, (t+2)*64, pB2, wave, lane);                    \
        __builtin_amdgcn_sched_barrier(0);                                     \
        __builtin_amdgcn_s_barrier();                                          \
        asm volatile("s_waitcnt lgkmcnt(0)" ::: "memory");                     \
        __builtin_amdgcn_sched_barrier(0);                                     \
        __builtin_amdgcn_s_setprio(1);                                         \
        _Pragma("unroll")                                                      \
        for (int i = 0; i < 4; ++i)                                            \
            _Pragma("unroll")                                                  \
            for (int j = 0; j < 4; ++j)                                        \
                acc[i][j] = MFMA16(af1[i], bf1[j], acc[i][j]);                 \
        __builtin_amdgcn_s_setprio(0);                                         \
        if (t < 14) asm volatile("s_waitcnt vmcnt(6)" ::: "memory");           \
        else        asm volatile("s_waitcnt vmcnt(0)" ::: "memory");           \
        __builtin_amdgcn_sched_barrier(0);                                     \
        __builtin_amdgcn_s_barrier();                                          \
        _Float16* tA = pA0; pA0 = pA1; pA1 = pA2; pA2 = tA;                    \
        _Float16* tB = pB0; pB0 = pB1; pB1 = pB2; pB2 = tB;                    \
    }

// ---- fused QKV projection GEMM: C = X * W^T + b, 128x256 tile ----
// grid 768: xcd = id&7; per-XCD 4m x 4n supertile (3MB < 4MB L2).
__global__ void __launch_bounds__(512) gemm_qkv(
    const _Float16* __restrict__ Xh, const _Float16* __restrict__ wt,
    const float* __restrict__ bq, const float* __restrict__ bk, const float* __restrict__ bv,
    _Float16* __restrict__ Q, _Float16* __restrict__ K, _Float16* __restrict__ Vt)
{
    __shared__ __align__(16) _Float16 sA[3][8192];    // 3 x 128x64
    __shared__ __align__(16) _Float16 sB[3][16384];   // 3 x 256x64

    const int id = blockIdx.x;        // 0..767
    const int xcd = id & 7;
    const int lid = id >> 3;          // 0..95
    const int ng  = lid >> 5;         // 0..2
    const int rem = lid & 31;
    const int mq  = rem >> 4;         // 0..1
    const int r2  = rem & 15;
    const int m_lo = r2 >> 2;         // 0..3
    const int nb   = r2 & 3;          // 0..3
    const int mblk = (mq*4 + m_lo)*8 + xcd;   // 0..63
    const int nblk = ng*4 + nb;               // 0..11

    const int tid = threadIdx.x;
    const int wave = tid >> 6, lane = tid & 63;
    const int wr = wave & 1, wc = wave >> 1;  // 2M x 4N
    const int q4 = lane >> 4, cc = lane & 15;

    const int mat = nblk >> 2;               // 0=q 1=k 2=v
    const int colbase = (nblk & 3) * 256;
    const _Float16* Bg = wt + (size_t)mat*1048576 + (size_t)colbase*1024;
    const _Float16* Ag = Xh + (size_t)mblk*131072;

    _Float16 *pA0 = &sA[0][0], *pA1 = &sA[1][0], *pA2 = &sA[2][0];
    _Float16 *pB0 = &sB[0][0], *pB1 = &sB[1][0], *pB2 = &sB[2][0];

    f32x4 acc[4][4] = {};

    GEMM_PIPE_LOOP()

    const float* bias = (mat==0)?bq:(mat==1)?bk:bv;
    const float QSCALE = 0.125f * 1.44269504f;
    #pragma unroll
    for (int i=0;i<4;i++)
      #pragma unroll
      for (int j=0;j<4;j++)
        #pragma unroll
        for (int r=0;r<4;r++){
            int m = mblk*128 + wr*64 + i*16 + q4*4 + r;
            int ncol = colbase + wc*64 + j*16 + cc;     // 0..1023 in matrix
            float val = acc[i][j][r] + bias[ncol];
            int b = m >> 11, s = m & 2047;
            int h = ncol >> 6, dk = ncol & 63;
            if (mat == 2) {
                Vt[((size_t)(b*16+h)*64 + dk)*2048 + s] = (_Float16)val;  // V^T: (B,H,DK,S)
            } else {
                size_t qi = ((size_t)(b*16+h)*2048 + s)*64 + dk;          // (B,H,S,DK)
                if (mat == 0) Q[qi] = (_Float16)(val * QSCALE);
                else          K[qi] = (_Float16)val;
            }
        }
}

// ---- output projection: out = ctx * Wo^T + bo, 128x256 tile ----
// grid 256 = one exact resident round; per-XCD 4m x 4n supertile (3MB).
__global__ void __launch_bounds__(512) gemm_out(
    const _Float16* __restrict__ Ctx, const _Float16* __restrict__ wt,
    const float* __restrict__ bo,
    float* __restrict__ out)
{
    __shared__ __align__(16) _Float16 sA[3][8192];
    __shared__ __align__(16) _Float16 sB[3][16384];

    const int id = blockIdx.x;        // 0..255
    const int xcd = id & 7;
    const int lid = id >> 3;          // 0..31
    const int mq  = lid >> 4;         // 0..1
    const int r2  = lid & 15;
    const int m_lo = r2 >> 2;         // 0..3
    const int nblk = r2 & 3;          // 0..3
    const int mblk = (mq*4 + m_lo)*8 + xcd;   // 0..63

    const int tid = threadIdx.x;
    const int wave = tid >> 6, lane = tid & 63;
    const int wr = wave & 1, wc = wave >> 1;
    const int q4 = lane >> 4, cc = lane & 15;

    const _Float16* Bg = wt + (size_t)3*1048576 + (size_t)nblk*256*1024;
    const _Float16* Ag = Ctx + (size_t)mblk*131072;

    _Float16 *pA0 = &sA[0][0], *pA1 = &sA[1][0], *pA2 = &sA[2][0];
    _Float16 *pB0 = &sB[0][0], *pB1 = &sB[1][0], *pB2 = &sB[2][0];

    f32x4 acc[4][4] = {};

    GEMM_PIPE_LOOP()

    #pragma unroll
    for (int i=0;i<4;i++)
      #pragma unroll
      for (int j=0;j<4;j++)
        #pragma unroll
        for (int r=0;r<4;r++){
            int m = mblk*128 + wr*64 + i*16 + q4*4 + r;
            int n = nblk*256 + wc*64 + j*16 + cc;
            out[(size_t)m*1024 + n] = acc[i][j][r] + bo[n];
        }
}

// ---- flash attention, static-max softmax: 128 q-rows/block, 64-key tiles ----
// 1-D grid 1024: XCD = id%8; 4 blocks/CU = one exact resident round.
// Double-buffered K/V tiles via global_load_lds with source-granule XOR
// swizzle; per tile: issue next-tile DMA -> compute -> vmcnt(0) -> barrier.
__global__ void __launch_bounds__(256,4) attn(
    const _Float16* __restrict__ Qg, const _Float16* __restrict__ Kg,
    const _Float16* __restrict__ Vg,
    _Float16* __restrict__ Ctx)
{
    __shared__ __align__(16) _Float16 sK[2][4096];   // 64 keys x 64 dims
    __shared__ __align__(16) _Float16 sV[2][4096];   // 64 dims x 64 keys
    __shared__ float sL[128];

    const int id = blockIdx.x;
    const int xcd = id & 7;
    const int t2 = id >> 3;           // 0..127
    const int qc = t2 & 15;
    const int bh = (t2 >> 4) * 8 + xcd;

    const int tid = threadIdx.x;
    const int wave = tid >> 6, lane = tid & 63;
    const int q4 = lane >> 4, cc = lane & 15;

    const size_t hoff = (size_t)bh * 131072;   // 2048*64
    const _Float16* Qp = Qg + hoff;
    const _Float16* Kp = Kg + hoff;
    const _Float16* Vp = Vg + hoff;

    const int qbase = qc*128 + wave*32;

    f16x8 qf[2][2];
    #pragma unroll
    for (int m=0;m<2;m++)
      #pragma unroll
      for (int ks=0;ks<2;ks++)
        qf[m][ks] = *(const f16x8*)&Qp[(qbase+m*16+cc)*64 + ks*32 + q4*8];

    f32x4 o[2][4] = {};
    float lsum[2] = {0.f, 0.f};

    // ---- precomputed loop-invariant offsets (element units) ----
    const int srow = tid >> 3;
    const int scg  = ((tid & 7) ^ ((tid >> 3) & 7)) * 8;
    int kofs[2], vofs[2], dofs[2];
    #pragma unroll
    for (int rr = 0; rr < 2; ++rr) {
        kofs[rr] = (rr*32 + srow)*64 + scg;
        vofs[rr] = (rr*32 + srow)*2048 + scg;
        dofs[rr] = rr*2048 + wave*512;
    }
    int okA[4], okB[4];
    #pragma unroll
    for (int kj=0;kj<4;kj++){
        okA[kj] = (kj*16+cc)*64 + ((q4    ^(cc&7))*8);
        okB[kj] = (kj*16+cc)*64 + (((4+q4)^(cc&7))*8);
    }
    int ov[2][4];
    #pragma unroll
    for (int ks=0;ks<2;ks++)
      #pragma unroll
      for (int v=0;v<4;v++)
        ov[ks][v] = (v*16+cc)*64 + (((ks*4+q4)^(cc&7))*8);

    // prologue: stage tile 0 into buffer 0
    #pragma unroll
    for (int rr = 0; rr < 2; ++rr) {
        async_cp16(Kp + kofs[rr], &sK[0][dofs[rr]]);
        async_cp16(Vp + vofs[rr], &sV[0][dofs[rr]]);
    }
    asm volatile("s_waitcnt vmcnt(0)" ::: "memory");
    __syncthreads();
    __builtin_amdgcn_sched_barrier(0);

    const _Float16* KbN = Kp + 4096;   // next-tile bases, strength-reduced
    const _Float16* VbN = Vp + 64;

    #pragma unroll 2
    for (int kt = 0; kt < 32; ++kt) {
        const int cur = kt & 1;
        const _Float16* kc = &sK[cur][0];
        const _Float16* vc = &sV[cur][0];

        // issue next tile's DMA into the OTHER buffer (hidden under compute)
        if (kt < 31) {
            _Float16* kn = &sK[cur ^ 1][0];
            _Float16* vn = &sV[cur ^ 1][0];
            #pragma unroll
            for (int rr = 0; rr < 2; ++rr) {
                async_cp16(KbN + kofs[rr], kn + dofs[rr]);
                async_cp16(VbN + vofs[rr], vn + dofs[rr]);
            }
        }

        // compute on current tile: per k-slice ks (32 keys), kj pair -> QK^T
        // -> exp2 -> pack -> permlane exchange -> PV.
        #pragma unroll
        for (int ks=0;ks<2;ks++){
            unsigned Ud[2][2], Wd[2][2];   // [m][dword]; U: kj=2ks, W: kj=2ks+1
            #pragma unroll
            for (int aa=0;aa<2;aa++){
                int kj = ks*2 + aa;
                f16x8 k0 = *(const f16x8*)&kc[okA[kj]];
                f16x8 k1 = *(const f16x8*)&kc[okB[kj]];
                #pragma unroll
                for (int m=0;m<2;m++){
                    f32x4 z = {};
                    f32x4 s = MFMA16(k0, qf[m][0], z);
                    s = MFMA16(k1, qf[m][1], s);
                    float p0 = __builtin_amdgcn_exp2f(s[0]);
                    float p1 = __builtin_amdgcn_exp2f(s[1]);
                    float p2 = __builtin_amdgcn_exp2f(s[2]);
                    float p3 = __builtin_amdgcn_exp2f(s[3]);
                    lsum[m] += (p0 + p1) + (p2 + p3);
                    unsigned d0 = __builtin_bit_cast(unsigned, pk(p0, p1));
                    unsigned d1 = __builtin_bit_cast(unsigned, pk(p2, p3));
                    if (aa == 0) { Ud[m][0] = d0; Ud[m][1] = d1; }
                    else         { Wd[m][0] = d0; Wd[m][1] = d1; }
                }
            }
            // A-frag: lane (cc,q4) needs keys 32ks+8q4+{0..7} of q-row cc.
            f16x8 pa[2];
            #pragma unroll
            for (int m=0;m<2;m++){
                u32x2 x0 = __builtin_amdgcn_permlane32_swap(Ud[m][0], Wd[m][0], false, false);
                u32x2 r02 = __builtin_amdgcn_permlane16_swap(x0[0], x0[1], false, false);
                u32x2 x1 = __builtin_amdgcn_permlane32_swap(Ud[m][1], Wd[m][1], false, false);
                u32x2 r13 = __builtin_amdgcn_permlane16_swap(x1[0], x1[1], false, false);
                u32x4 pw;
                pw[0] = r02[0]; pw[1] = r13[0]; pw[2] = r02[1]; pw[3] = r13[1];
                pa[m] = __builtin_bit_cast(f16x8, pw);
            }
            #pragma unroll
            for (int v=0;v<4;v++){
                f16x8 vf = *(const f16x8*)&vc[ov[ks][v]];
                o[0][v] = MFMA16(pa[0], vf, o[0][v]);
                o[1][v] = MFMA16(pa[1], vf, o[1][v]);
            }
        }

        KbN += 4096;
        VbN += 64;
        asm volatile("s_waitcnt vmcnt(0)" ::: "memory");
        __syncthreads();   // next tile staged + all reads of cur done
        __builtin_amdgcn_sched_barrier(0);
    }

    // row sums: lane holds partial for q-row cc; reduce over the 4 q4-lanes,
    // then transpose cc -> (q4*4+r) through a tiny LDS buffer.
    #pragma unroll
    for (int m=0;m<2;m++){
        lsum[m] += __shfl_xor(lsum[m], 16, 64);
        lsum[m] += __shfl_xor(lsum[m], 32, 64);
    }
    if (q4 == 0) {
        sL[wave*32 + cc]      = lsum[0];
        sL[wave*32 + 16 + cc] = lsum[1];
    }
    __syncthreads();

    int b = bh >> 4, h = bh & 15;
    #pragma unroll
    for (int m=0;m<2;m++)
      #pragma unroll
      for (int r=0;r<4;r++){
        float inv = 1.f / sL[wave*32 + m*16 + q4*4 + r];
        int s = qbase + m*16 + q4*4 + r;
        #pragma unroll
        for (int v=0;v<4;v++){
            float val = o[m][v][r]*inv;
            int dk = v*16 + cc;
            Ctx[((size_t)(b*2048+s)*16 + h)*64 + dk] = (_Float16)val;  // (B,S,H,DK)
        }
      }
}

extern "C" void kernel_launch(void* const* d_in, const int* in_sizes, int n_in,
                              void* d_out, int out_size, void* d_ws, size_t ws_size,
                              hipStream_t stream)
{
    const float* q  = (const float*)d_in[0];
    const float* Wq = (const float*)d_in[1];
    const float* bq = (const float*)d_in[2];
    const float* Wk = (const float*)d_in[3];
    const float* bk = (const float*)d_in[4];
    const float* Wv = (const float*)d_in[5];
    const float* bv = (const float*)d_in[6];
    const float* Wo = (const float*)d_in[7];
    const float* bo = (const float*)d_in[8];
    float* out = (float*)d_out;

    _Float16* ws  = (_Float16*)d_ws;
    _Float16* wt  = ws;                   // 4 x 1M fp16 = 8MB
    _Float16* Xh  = ws + 4194304;         // 16MB
    _Float16* Q   = ws + 12582912;
    _Float16* K   = ws + 20971520;
    _Float16* Vt  = ws + 29360128;        // end 37748736 el = 75.5MB
    _Float16* Ctx = Xh;                   // X dead after gemm_qkv

    prep_weights<<<dim3(1024,4), 256, 0, stream>>>(Wq, Wk, Wv, Wo, wt);
    cvt_x<<<dim3(8192), 256, 0, stream>>>(q, Xh);
    gemm_qkv<<<dim3(768), 512, 0, stream>>>(Xh, wt, bq, bk, bv, Q, K, Vt);
    attn<<<dim3(1024), 256, 0, stream>>>(Q, K, Vt, Ctx);
    gemm_out<<<dim3(256), 512, 0, stream>>>(Ctx, wt, bo, out);
}

// Round 11
// 274.084 us; speedup vs baseline: 1.1444x; 1.0197x over previous
//
#include <hip/hip_runtime.h>
#include <hip/hip_bf16.h>
#include <math.h>

// MultiheadAttention: B=4,S=2048,E=1024,H=16,DK=64, fp32 in/out.
// All-fp16 MFMA; static-max softmax in exp2 domain.
// GEMMs v5 (R9/R10): fine-phase triple-buffered pipeline + L2 supertile walk.
// attn v9 = R10 body + row-sum moved BACK to ones-MFMA: R10 counters show
// VALUBusy 50% > MfmaUtil 35% -> lsum's ~24 VALU adds/tile belong on the
// matrix pipe (+4 MFMA/tile on 15pts of slack); also deletes the epilogue
// shuffle + sL LDS transpose (the R1-era removal was right when MFMA was
// the constraint; the constraint flipped).
// prep_weights + cvt_x merged into one launch (independent work, one gap).

typedef _Float16 f16x8 __attribute__((ext_vector_type(8)));
typedef _Float16 f16x4 __attribute__((ext_vector_type(4)));
typedef _Float16 f16x2 __attribute__((ext_vector_type(2)));
typedef float    f32x4 __attribute__((ext_vector_type(4)));
typedef unsigned int u32x2 __attribute__((ext_vector_type(2)));
typedef unsigned int u32x4 __attribute__((ext_vector_type(4)));

#define MFMA16(a,b,c) __builtin_amdgcn_mfma_f32_16x16x32_f16(a,b,c,0,0,0)

__device__ __forceinline__ void async_cp16(const _Float16* g, _Float16* l) {
    __builtin_amdgcn_global_load_lds(
        (const __attribute__((address_space(1))) unsigned int*)g,
        (__attribute__((address_space(3))) unsigned int*)l,
        16, 0, 0);
}

__device__ __forceinline__ f16x2 pk(float a, float b) {
    return __builtin_bit_cast(f16x2, __builtin_amdgcn_cvt_pkrtz(a, b));
}

// ---- merged prep: X fp32->fp16 (blocks 0..8191) and weight transpose+cvt
// W (K x N) -> WT fp16 (N x K) (blocks 8192..12287). Independent paths.
__global__ void __launch_bounds__(256) prep(
    const float* __restrict__ X,
    const float* __restrict__ Wq, const float* __restrict__ Wk,
    const float* __restrict__ Wv, const float* __restrict__ Wo,
    _Float16* __restrict__ Xh, _Float16* __restrict__ wt)
{
    __shared__ float tile[32][33];
    const int bx = blockIdx.x;
    if (bx < 8192) {
        int i = (bx*256 + threadIdx.x)*4;
        f32x4 x = *(const f32x4*)&X[i];
        f16x4 h;
        #pragma unroll
        for (int k=0;k<4;k++) h[k] = (_Float16)x[k];
        *(f16x4*)&Xh[i] = h;
        return;
    }
    int t = bx - 8192;               // 0..4095
    int mat = t >> 10;
    int tloc = t & 1023;
    const float* W = (mat==0)?Wq:(mat==1)?Wk:(mat==2)?Wv:Wo;
    _Float16* WT = wt + (size_t)mat*1048576;
    int kb = (tloc & 31) * 32;
    int nb = (tloc >> 5) * 32;
    int tx = threadIdx.x & 31, ty = threadIdx.x >> 5;   // ty 0..7
    #pragma unroll
    for (int r = 0; r < 4; ++r) {
        int row = ty + r*8;
        tile[row][tx] = W[(size_t)(kb+row)*1024 + nb + tx];
    }
    __syncthreads();
    #pragma unroll
    for (int r = 0; r < 4; ++r) {
        int row = ty + r*8;
        WT[(size_t)(nb+row)*1024 + kb + tx] = (_Float16)tile[tx][row];
    }
}

// ---- GEMM staging: A tile 128x64 (2 load-rounds), B tile 256x64 (4 rounds).
__device__ __forceinline__ void stage3a(
    const _Float16* __restrict__ Ag, const _Float16* __restrict__ Bg, int kb,
    _Float16* sAb, _Float16* sBb, int wave, int lane)
{
    #pragma unroll
    for (int j = 0; j < 2; ++j) {
        int d   = j*512 + wave*64 + lane;
        int row = d >> 3;
        int sg  = (d & 7) ^ (row & 7);
        async_cp16(&Ag[(size_t)row*1024 + kb + sg*8], sAb + (j*512 + wave*64)*8);
    }
    {
        int d   = wave*64 + lane;
        int row = d >> 3;
        int sg  = (d & 7) ^ (row & 7);
        async_cp16(&Bg[(size_t)row*1024 + kb + sg*8], sBb + (wave*64)*8);
    }
}
__device__ __forceinline__ void stage3b(
    const _Float16* __restrict__ Bg, int kb, _Float16* sBb, int wave, int lane)
{
    #pragma unroll
    for (int j = 1; j < 4; ++j) {
        int d   = j*512 + wave*64 + lane;
        int row = d >> 3;
        int sg  = (d & 7) ^ (row & 7);
        async_cp16(&Bg[(size_t)row*1024 + kb + sg*8], sBb + (j*512 + wave*64)*8);
    }
}

// K-loop: 16 tiles, buffers rotate over 3; tile t computes from pA0/pB0 while
// tile t+2 streams into pA2/pB2. Per tile two fine phases; counted vmcnt(6).
#define GEMM_PIPE_LOOP()                                                       \
    stage3a(Ag, Bg, 0,  pA0, pB0, wave, lane);                                 \
    stage3b(Bg, 0,  pB0, wave, lane);                                          \
    stage3a(Ag, Bg, 64, pA1, pB1, wave, lane);                                 \
    stage3b(Bg, 64, pB1, wave, lane);                                          \
    asm volatile("s_waitcnt vmcnt(6)" ::: "memory");                           \
    __builtin_amdgcn_s_barrier();                                              \
    __builtin_amdgcn_sched_barrier(0);                                         \
    for (int t = 0; t < 16; ++t) {                                             \
        f16x8 af0[4], bf0[4];                                                  \
        _Pragma("unroll")                                                      \
        for (int i = 0; i < 4; ++i)                                            \
            af0[i] = *(const f16x8*)&pA0[(wr*64+i*16+cc)*64 +                  \
                                         ((q4^(cc&7))*8)];                     \
        _Pragma("unroll")                                                      \
        for (int j = 0; j < 4; ++j)                                            \
            bf0[j] = *(const f16x8*)&pB0[(wc*64+j*16+cc)*64 +                  \
                                         ((q4^(cc&7))*8)];                     \
        if (t < 14) stage3a(Ag, Bg, (t+2)*64, pA2, pB2, wave, lane);           \
        __builtin_amdgcn_sched_barrier(0);                                     \
        __builtin_amdgcn_s_barrier();                                          \
        asm volatile("s_waitcnt lgkmcnt(0)" ::: "memory");                     \
        __builtin_amdgcn_sched_barrier(0);                                     \
        __builtin_amdgcn_s_setprio(1);                                         \
        _Pragma("unroll")                                                      \
        for (int i = 0; i < 4; ++i)                                            \
            _Pragma("unroll")                                                  \
            for (int j = 0; j < 4; ++j)                                        \
                acc[i][j] = MFMA16(af0[i], bf0[j], acc[i][j]);                 \
        __builtin_amdgcn_s_setprio(0);                                         \
        __builtin_amdgcn_sched_barrier(0);                                     \
        __builtin_amdgcn_s_barrier();                                          \
        f16x8 af1[4], bf1[4];                                                  \
        _Pragma("unroll")                                                      \
        for (int i = 0; i < 4; ++i)                                            \
            af1[i] = *(const f16x8*)&pA0[(wr*64+i*16+cc)*64 +                  \
                                         (((4+q4)^(cc&7))*8)];                 \
        _Pragma("unroll")                                                      \
        for (int j = 0; j < 4; ++j)                                            \
            bf1[j] = *(const f16x8*)&pB0[(wc*64+j*16+cc)*64 +                  \
                                         (((4+q4)^(cc&7))*8)];                 \
        if (t < 14) stage3b(Bg, (t+2)*64, pB2, wave, lane);                    \
        __builtin_amdgcn_sched_barrier(0);                                     \
        __builtin_amdgcn_s_barrier();                                          \
        asm volatile("s_waitcnt lgkmcnt(0)" ::: "memory");                     \
        __builtin_amdgcn_sched_barrier(0);                                     \
        __builtin_amdgcn_s_setprio(1);                                         \
        _Pragma("unroll")                                                      \
        for (int i = 0; i < 4; ++i)                                            \
            _Pragma("unroll")                                                  \
            for (int j = 0; j < 4; ++j)                                        \
                acc[i][j] = MFMA16(af1[i], bf1[j], acc[i][j]);                 \
        __builtin_amdgcn_s_setprio(0);                                         \
        if (t < 14) asm volatile("s_waitcnt vmcnt(6)" ::: "memory");           \
        else        asm volatile("s_waitcnt vmcnt(0)" ::: "memory");           \
        __builtin_amdgcn_sched_barrier(0);                                     \
        __builtin_amdgcn_s_barrier();                                          \
        _Float16* tA = pA0; pA0 = pA1; pA1 = pA2; pA2 = tA;                    \
        _Float16* tB = pB0; pB0 = pB1; pB1 = pB2; pB2 = tB;                    \
    }

// ---- fused QKV projection GEMM: C = X * W^T + b, 128x256 tile ----
// grid 768: xcd = id&7; per-XCD 4m x 4n supertile (3MB < 4MB L2).
__global__ void __launch_bounds__(512) gemm_qkv(
    const _Float16* __restrict__ Xh, const _Float16* __restrict__ wt,
    const float* __restrict__ bq, const float* __restrict__ bk, const float* __restrict__ bv,
    _Float16* __restrict__ Q, _Float16* __restrict__ K, _Float16* __restrict__ Vt)
{
    __shared__ __align__(16) _Float16 sA[3][8192];    // 3 x 128x64
    __shared__ __align__(16) _Float16 sB[3][16384];   // 3 x 256x64

    const int id = blockIdx.x;        // 0..767
    const int xcd = id & 7;
    const int lid = id >> 3;          // 0..95
    const int ng  = lid >> 5;         // 0..2
    const int rem = lid & 31;
    const int mq  = rem >> 4;         // 0..1
    const int r2  = rem & 15;
    const int m_lo = r2 >> 2;         // 0..3
    const int nb   = r2 & 3;          // 0..3
    const int mblk = (mq*4 + m_lo)*8 + xcd;   // 0..63
    const int nblk = ng*4 + nb;               // 0..11

    const int tid = threadIdx.x;
    const int wave = tid >> 6, lane = tid & 63;
    const int wr = wave & 1, wc = wave >> 1;  // 2M x 4N
    const int q4 = lane >> 4, cc = lane & 15;

    const int mat = nblk >> 2;               // 0=q 1=k 2=v
    const int colbase = (nblk & 3) * 256;
    const _Float16* Bg = wt + (size_t)mat*1048576 + (size_t)colbase*1024;
    const _Float16* Ag = Xh + (size_t)mblk*131072;

    _Float16 *pA0 = &sA[0][0], *pA1 = &sA[1][0], *pA2 = &sA[2][0];
    _Float16 *pB0 = &sB[0][0], *pB1 = &sB[1][0], *pB2 = &sB[2][0];

    f32x4 acc[4][4] = {};

    GEMM_PIPE_LOOP()

    const float* bias = (mat==0)?bq:(mat==1)?bk:bv;
    const float QSCALE = 0.125f * 1.44269504f;
    #pragma unroll
    for (int i=0;i<4;i++)
      #pragma unroll
      for (int j=0;j<4;j++)
        #pragma unroll
        for (int r=0;r<4;r++){
            int m = mblk*128 + wr*64 + i*16 + q4*4 + r;
            int ncol = colbase + wc*64 + j*16 + cc;     // 0..1023 in matrix
            float val = acc[i][j][r] + bias[ncol];
            int b = m >> 11, s = m & 2047;
            int h = ncol >> 6, dk = ncol & 63;
            if (mat == 2) {
                Vt[((size_t)(b*16+h)*64 + dk)*2048 + s] = (_Float16)val;  // V^T: (B,H,DK,S)
            } else {
                size_t qi = ((size_t)(b*16+h)*2048 + s)*64 + dk;          // (B,H,S,DK)
                if (mat == 0) Q[qi] = (_Float16)(val * QSCALE);
                else          K[qi] = (_Float16)val;
            }
        }
}

// ---- output projection: out = ctx * Wo^T + bo, 128x256 tile ----
// grid 256 = one exact resident round; per-XCD 4m x 4n supertile (3MB).
__global__ void __launch_bounds__(512) gemm_out(
    const _Float16* __restrict__ Ctx, const _Float16* __restrict__ wt,
    const float* __restrict__ bo,
    float* __restrict__ out)
{
    __shared__ __align__(16) _Float16 sA[3][8192];
    __shared__ __align__(16) _Float16 sB[3][16384];

    const int id = blockIdx.x;        // 0..255
    const int xcd = id & 7;
    const int lid = id >> 3;          // 0..31
    const int mq  = lid >> 4;         // 0..1
    const int r2  = lid & 15;
    const int m_lo = r2 >> 2;         // 0..3
    const int nblk = r2 & 3;          // 0..3
    const int mblk = (mq*4 + m_lo)*8 + xcd;   // 0..63

    const int tid = threadIdx.x;
    const int wave = tid >> 6, lane = tid & 63;
    const int wr = wave & 1, wc = wave >> 1;
    const int q4 = lane >> 4, cc = lane & 15;

    const _Float16* Bg = wt + (size_t)3*1048576 + (size_t)nblk*256*1024;
    const _Float16* Ag = Ctx + (size_t)mblk*131072;

    _Float16 *pA0 = &sA[0][0], *pA1 = &sA[1][0], *pA2 = &sA[2][0];
    _Float16 *pB0 = &sB[0][0], *pB1 = &sB[1][0], *pB2 = &sB[2][0];

    f32x4 acc[4][4] = {};

    GEMM_PIPE_LOOP()

    #pragma unroll
    for (int i=0;i<4;i++)
      #pragma unroll
      for (int j=0;j<4;j++)
        #pragma unroll
        for (int r=0;r<4;r++){
            int m = mblk*128 + wr*64 + i*16 + q4*4 + r;
            int n = nblk*256 + wc*64 + j*16 + cc;
            out[(size_t)m*1024 + n] = acc[i][j][r] + bo[n];
        }
}

// ---- flash attention, static-max softmax: 128 q-rows/block, 64-key tiles ----
// 1-D grid 1024: XCD = id%8; 4 blocks/CU = one exact resident round.
// Double-buffered K/V tiles via global_load_lds with source-granule XOR
// swizzle; per tile: issue next-tile DMA -> compute -> vmcnt(0) -> barrier.
// Row sums via ones-MFMA (oL, same C layout as o -> inv = 1/oL[m][r],
// no shuffles / no LDS transpose).
__global__ void __launch_bounds__(256,4) attn(
    const _Float16* __restrict__ Qg, const _Float16* __restrict__ Kg,
    const _Float16* __restrict__ Vg,
    _Float16* __restrict__ Ctx)
{
    __shared__ __align__(16) _Float16 sK[2][4096];   // 64 keys x 64 dims
    __shared__ __align__(16) _Float16 sV[2][4096];   // 64 dims x 64 keys

    const int id = blockIdx.x;
    const int xcd = id & 7;
    const int t2 = id >> 3;           // 0..127
    const int qc = t2 & 15;
    const int bh = (t2 >> 4) * 8 + xcd;

    const int tid = threadIdx.x;
    const int wave = tid >> 6, lane = tid & 63;
    const int q4 = lane >> 4, cc = lane & 15;

    const size_t hoff = (size_t)bh * 131072;   // 2048*64
    const _Float16* Qp = Qg + hoff;
    const _Float16* Kp = Kg + hoff;
    const _Float16* Vp = Vg + hoff;

    const int qbase = qc*128 + wave*32;

    f16x8 qf[2][2];
    #pragma unroll
    for (int m=0;m<2;m++)
      #pragma unroll
      for (int ks=0;ks<2;ks++)
        qf[m][ks] = *(const f16x8*)&Qp[(qbase+m*16+cc)*64 + ks*32 + q4*8];

    f16x8 vones;
    #pragma unroll
    for (int k=0;k<8;k++) vones[k] = (_Float16)1.0f;

    f32x4 o[2][4] = {};
    f32x4 oL[2] = {};   // row sums via ones-MFMA, same layout as o

    // ---- precomputed loop-invariant offsets (element units) ----
    const int srow = tid >> 3;
    const int scg  = ((tid & 7) ^ ((tid >> 3) & 7)) * 8;
    int kofs[2], vofs[2], dofs[2];
    #pragma unroll
    for (int rr = 0; rr < 2; ++rr) {
        kofs[rr] = (rr*32 + srow)*64 + scg;
        vofs[rr] = (rr*32 + srow)*2048 + scg;
        dofs[rr] = rr*2048 + wave*512;
    }
    int okA[4], okB[4];
    #pragma unroll
    for (int kj=0;kj<4;kj++){
        okA[kj] = (kj*16+cc)*64 + ((q4    ^(cc&7))*8);
        okB[kj] = (kj*16+cc)*64 + (((4+q4)^(cc&7))*8);
    }
    int ov[2][4];
    #pragma unroll
    for (int ks=0;ks<2;ks++)
      #pragma unroll
      for (int v=0;v<4;v++)
        ov[ks][v] = (v*16+cc)*64 + (((ks*4+q4)^(cc&7))*8);

    // prologue: stage tile 0 into buffer 0
    #pragma unroll
    for (int rr = 0; rr < 2; ++rr) {
        async_cp16(Kp + kofs[rr], &sK[0][dofs[rr]]);
        async_cp16(Vp + vofs[rr], &sV[0][dofs[rr]]);
    }
    asm volatile("s_waitcnt vmcnt(0)" ::: "memory");
    __syncthreads();
    __builtin_amdgcn_sched_barrier(0);

    const _Float16* KbN = Kp + 4096;   // next-tile bases, strength-reduced
    const _Float16* VbN = Vp + 64;

    #pragma unroll 2
    for (int kt = 0; kt < 32; ++kt) {
        const int cur = kt & 1;
        const _Float16* kc = &sK[cur][0];
        const _Float16* vc = &sV[cur][0];

        // issue next tile's DMA into the OTHER buffer (hidden under compute)
        if (kt < 31) {
            _Float16* kn = &sK[cur ^ 1][0];
            _Float16* vn = &sV[cur ^ 1][0];
            #pragma unroll
            for (int rr = 0; rr < 2; ++rr) {
                async_cp16(KbN + kofs[rr], kn + dofs[rr]);
                async_cp16(VbN + vofs[rr], vn + dofs[rr]);
            }
        }

        // compute on current tile: per k-slice ks (32 keys), kj pair -> QK^T
        // -> exp2 -> pack -> permlane exchange -> PV + ones-MFMA row sum.
        #pragma unroll
        for (int ks=0;ks<2;ks++){
            unsigned Ud[2][2], Wd[2][2];   // [m][dword]; U: kj=2ks, W: kj=2ks+1
            #pragma unroll
            for (int aa=0;aa<2;aa++){
                int kj = ks*2 + aa;
                f16x8 k0 = *(const f16x8*)&kc[okA[kj]];
                f16x8 k1 = *(const f16x8*)&kc[okB[kj]];
                #pragma unroll
                for (int m=0;m<2;m++){
                    f32x4 z = {};
                    f32x4 s = MFMA16(k0, qf[m][0], z);
                    s = MFMA16(k1, qf[m][1], s);
                    float p0 = __builtin_amdgcn_exp2f(s[0]);
                    float p1 = __builtin_amdgcn_exp2f(s[1]);
                    float p2 = __builtin_amdgcn_exp2f(s[2]);
                    float p3 = __builtin_amdgcn_exp2f(s[3]);
                    unsigned d0 = __builtin_bit_cast(unsigned, pk(p0, p1));
                    unsigned d1 = __builtin_bit_cast(unsigned, pk(p2, p3));
                    if (aa == 0) { Ud[m][0] = d0; Ud[m][1] = d1; }
                    else         { Wd[m][0] = d0; Wd[m][1] = d1; }
                }
            }
            // A-frag: lane (cc,q4) needs keys 32ks+8q4+{0..7} of q-row cc.
            f16x8 pa[2];
            #pragma unroll
            for (int m=0;m<2;m++){
                u32x2 x0 = __builtin_amdgcn_permlane32_swap(Ud[m][0], Wd[m][0], false, false);
                u32x2 r02 = __builtin_amdgcn_permlane16_swap(x0[0], x0[1], false, false);
                u32x2 x1 = __builtin_amdgcn_permlane32_swap(Ud[m][1], Wd[m][1], false, false);
                u32x2 r13 = __builtin_amdgcn_permlane16_swap(x1[0], x1[1], false, false);
                u32x4 pw;
                pw[0] = r02[0]; pw[1] = r13[0]; pw[2] = r02[1]; pw[3] = r13[1];
                pa[m] = __builtin_bit_cast(f16x8, pw);
            }
            #pragma unroll
            for (int v=0;v<4;v++){
                f16x8 vf = *(const f16x8*)&vc[ov[ks][v]];
                o[0][v] = MFMA16(pa[0], vf, o[0][v]);
                o[1][v] = MFMA16(pa[1], vf, o[1][v]);
            }
            oL[0] = MFMA16(pa[0], vones, oL[0]);
            oL[1] = MFMA16(pa[1], vones, oL[1]);
        }

        KbN += 4096;
        VbN += 64;
        asm volatile("s_waitcnt vmcnt(0)" ::: "memory");
        __syncthreads();   // next tile staged + all reads of cur done
        __builtin_amdgcn_sched_barrier(0);
    }

    int b = bh >> 4, h = bh & 15;
    #pragma unroll
    for (int m=0;m<2;m++)
      #pragma unroll
      for (int r=0;r<4;r++){
        float inv = 1.f / oL[m][r];
        int s = qbase + m*16 + q4*4 + r;
        #pragma unroll
        for (int v=0;v<4;v++){
            float val = o[m][v][r]*inv;
            int dk = v*16 + cc;
            Ctx[((size_t)(b*2048+s)*16 + h)*64 + dk] = (_Float16)val;  // (B,S,H,DK)
        }
      }
}

extern "C" void kernel_launch(void* const* d_in, const int* in_sizes, int n_in,
                              void* d_out, int out_size, void* d_ws, size_t ws_size,
                              hipStream_t stream)
{
    const float* q  = (const float*)d_in[0];
    const float* Wq = (const float*)d_in[1];
    const float* bq = (const float*)d_in[2];
    const float* Wk = (const float*)d_in[3];
    const float* bk = (const float*)d_in[4];
    const float* Wv = (const float*)d_in[5];
    const float* bv = (const float*)d_in[6];
    const float* Wo = (const float*)d_in[7];
    const float* bo = (const float*)d_in[8];
    float* out = (float*)d_out;

    _Float16* ws  = (_Float16*)d_ws;
    _Float16* wt  = ws;                   // 4 x 1M fp16 = 8MB
    _Float16* Xh  = ws + 4194304;         // 16MB
    _Float16* Q   = ws + 12582912;
    _Float16* K   = ws + 20971520;
    _Float16* Vt  = ws + 29360128;        // end 37748736 el = 75.5MB
    _Float16* Ctx = Xh;                   // X dead after gemm_qkv

    prep<<<dim3(12288), 256, 0, stream>>>(q, Wq, Wk, Wv, Wo, Xh, wt);
    gemm_qkv<<<dim3(768), 512, 0, stream>>>(Xh, wt, bq, bk, bv, Q, K, Vt);
    attn<<<dim3(1024), 256, 0, stream>>>(Q, K, Vt, Ctx);
    gemm_out<<<dim3(256), 512, 0, stream>>>(Ctx, wt, bo, out);
}